// Round 11
// baseline (384.773 us; speedup 1.0000x reference)
//
#include <hip/hip_runtime.h>
#include <hip/hip_bf16.h>

typedef float  f32x4v __attribute__((ext_vector_type(4)));
typedef short  bf16x8 __attribute__((ext_vector_type(8)));

#define NFRAG   26
#define TB_F32  512                            // 16 tables x 32 f32
#define FRG_U16 (NFRAG*512)                    // 26 frags x 64 lanes x 8 bf16
#define SHARE_BYTES (TB_F32*4 + FRG_U16*2)     // 28672 B staged to LDS
#define SHARE_U4 (SHARE_BYTES/16)              // 1792 uint4
#define WC_OFF 7168                            // WC scratch offset in WS floats

#define BLK 512                                // 8 waves share one LDS image
#define COPY_BLOCKS 128
#define EDGE_BLOCKS 896
#define GRID (COPY_BLOCKS + EDGE_BLOCKS)       // 1024 = 4 blocks/CU = 32 waves/CU
#define EDGE_WAVES (EDGE_BLOCKS * 8)           // 7168

#define MFMA(a,b,c) __builtin_amdgcn_mfma_f32_16x16x32_bf16(a,b,c,0,0,0)

__device__ __forceinline__ float sigf(float v) { return 1.0f / (1.0f + __expf(-v)); }
__device__ __forceinline__ float tanhf_fast(float v) {
    float a = fabsf(v);
    float t = __expf(-2.0f * a);
    float r = (1.0f - t) / (1.0f + t);
    return v < 0.0f ? -r : r;
}
__device__ __forceinline__ unsigned pk(float a, float b) {   // bf16(a) lo | bf16(b) hi
    union { __hip_bfloat162 h; unsigned u; } c;
    c.h = __float22bfloat162_rn(make_float2(a, b));
    return c.u;
}

union FragU { uint4 u4; bf16x8 s8; unsigned u[4]; };

__device__ __forceinline__ bf16x8 ldfrag(const unsigned short* frg, int idx_u16) {
    FragU c; c.u4 = *(const uint4*)(frg + idx_u16); return c.s8;
}
__device__ __forceinline__ f32x4v tbl(const float* tb, int idx_f32) {
    return *(const f32x4v*)(tb + idx_f32);
}
// In-register D->B relayout (R9-verified): consumer A-frags are k-permuted so
// the lane's 8 D values ARE its B fragment. Zero cross-lane, zero LDS.
__device__ __forceinline__ bf16x8 relayout_reg(f32x4v h0, f32x4v h1) {
    FragU c;
    c.u[0] = pk(h0[0], h0[1]); c.u[1] = pk(h0[2], h0[3]);
    c.u[2] = pk(h1[0], h1[1]); c.u[3] = pk(h1[2], h1[3]);
    return c.s8;
}

__global__ void winner_k(const int* __restrict__ dst_ids, int* __restrict__ winner, int E) {
    int e = blockIdx.x * 256 + threadIdx.x;
    if (e < E) atomicMax(winner + dst_ids[e], e + 1);
}

__global__ void prep_k(const float* __restrict__ msg_W1, const float* __restrict__ msg_b1,
                       const float* __restrict__ msg_W2, const float* __restrict__ msg_b2,
                       const float* __restrict__ w_ih, const float* __restrict__ b_ih,
                       const float* __restrict__ w_hh, const float* __restrict__ b_hh,
                       const float* __restrict__ Wv, const float* __restrict__ bv,
                       const float* __restrict__ Wo, const float* __restrict__ bo,
                       const float* __restrict__ emb_W1, const float* __restrict__ emb_b1,
                       const float* __restrict__ emb_W2, const float* __restrict__ emb_b2,
                       const float* __restrict__ cls_W1, const float* __restrict__ cls_b1,
                       const float* __restrict__ cls_W2, float* __restrict__ WSf) {
    int t = threadIdx.x;  // one block, 256 threads
    float* tb = WSf;
    unsigned short* frg = (unsigned short*)(WSf + TB_F32);
    float* WC = WSf + WC_OFF;  // [32][32] folded Wo@Wv
    if (t < 32) {
        int j = t;
        tb[0*32+j]  = msg_b1[j];
        tb[1*32+j]  = msg_W1[j*67+64];
        tb[2*32+j]  = msg_W1[j*67+65];
        tb[3*32+j]  = msg_W1[j*67+66];
        tb[4*32+j]  = msg_b2[j];
        tb[5*32+j]  = b_ih[32+j] + b_hh[32+j];     // z bias
        tb[6*32+j]  = b_ih[j] + b_hh[j];           // r bias
        tb[7*32+j]  = b_hh[64+j];                  // h_n bias
        tb[8*32+j]  = b_ih[64+j];                  // i_n bias
        float a = bo[j];
        for (int o = 0; o < 32; ++o) a += Wo[j*32+o] * bv[o];
        tb[9*32+j]  = a;                           // folded attn bias
        tb[10*32+j] = emb_b1[j];
        tb[11*32+j] = emb_W1[j*34+32];
        tb[12*32+j] = emb_W1[j*34+33];
        tb[13*32+j] = emb_b2[j];
        tb[14*32+j] = cls_b1[j];
        tb[15*32+j] = cls_W2[j];
    }
    for (int i = t; i < 1024; i += 256) {
        int j = i >> 5, k = i & 31;
        float a = 0.0f;
        for (int o = 0; o < 32; ++o) a += Wo[j*32+o] * Wv[o*32+k];
        WC[i] = a;
    }
    __syncthreads();
    // A-fragment pack: frag f, lane l, elem i -> W[j0 + (l&15)][k0 + kidx]
    // kidx = kb (natural) or m(kb) for consumers of relayout_reg output.
    for (int idx = t; idx < NFRAG * 512; idx += 256) {
        int f = idx >> 9, l = (idx >> 3) & 63, i = idx & 7;
        int r = l & 15, kb = ((l >> 4) << 3) + i;
        const float* P; int j0 = 0, k0 = 0, ld = 32;
        bool mapped = false;
        switch (f) {
            case 0:  P = msg_W1; j0 = 0;  k0 = 0;  ld = 67; break;
            case 1:  P = msg_W1; j0 = 0;  k0 = 32; ld = 67; break;
            case 2:  P = msg_W1; j0 = 16; k0 = 0;  ld = 67; break;
            case 3:  P = msg_W1; j0 = 16; k0 = 32; ld = 67; break;
            case 4:  P = msg_W2; j0 = 0;  mapped = true; break;
            case 5:  P = msg_W2; j0 = 16; mapped = true; break;
            case 6:  P = w_ih;   j0 = 32; mapped = true; break;   // z ih
            case 7:  P = w_hh;   j0 = 32; break;                  // z hh
            case 8:  P = w_ih;   j0 = 48; mapped = true; break;
            case 9:  P = w_hh;   j0 = 48; break;
            case 10: P = w_ih;   j0 = 0;  mapped = true; break;   // r ih
            case 11: P = w_hh;   j0 = 0;  break;
            case 12: P = w_ih;   j0 = 16; mapped = true; break;
            case 13: P = w_hh;   j0 = 16; break;
            case 14: P = w_hh;   j0 = 64; break;                  // n hh
            case 15: P = w_hh;   j0 = 80; break;
            case 16: P = w_ih;   j0 = 64; mapped = true; break;   // n ih
            case 17: P = w_ih;   j0 = 80; mapped = true; break;
            case 18: P = WC;     j0 = 0;  break;                  // folded attn
            case 19: P = WC;     j0 = 16; break;
            case 20: P = emb_W1; j0 = 0;  ld = 34; mapped = true; break;
            case 21: P = emb_W1; j0 = 16; ld = 34; mapped = true; break;
            case 22: P = emb_W2; j0 = 0;  mapped = true; break;
            case 23: P = emb_W2; j0 = 16; mapped = true; break;
            case 24: P = cls_W1; j0 = 0;  mapped = true; break;
            default: P = cls_W1; j0 = 16; mapped = true; break;
        }
        int kidx = kb;
        if (mapped) kidx = 16 * ((kb >> 2) & 1) + 4 * (kb >> 3) + (kb & 3);
        __hip_bfloat16 hv = __float2bfloat16(P[(j0 + r) * ld + k0 + kidx]);
        frg[idx] = *(unsigned short*)&hv;
    }
}

__device__ __forceinline__ void compute16(
    int grp, int E, int eI, int g, int lane,
    int e, int dst, int winv, float2 ef, float dtv,
    f32x4v sa, f32x4v sb, f32x4v da, f32x4v db, f32x4v t0, f32x4v t1,
    const float* tb, const unsigned short* frg, float clsb2,
    float* __restrict__ probs, float* __restrict__ out_mem) {
    int ob = 0, tbo = 0;
    asm volatile("" : "+v"(ob), "+v"(tbo));  // block LICM of LDS frag/table reads

    FragU Bs, Bd;
    Bs.u[0] = pk(sa[0], sa[1]); Bs.u[1] = pk(sa[2], sa[3]);
    Bs.u[2] = pk(sb[0], sb[1]); Bs.u[3] = pk(sb[2], sb[3]);
    Bd.u[0] = pk(da[0], da[1]); Bd.u[1] = pk(da[2], da[3]);
    Bd.u[2] = pk(db[0], db[1]); Bd.u[3] = pk(db[2], db[3]);
    f32x4v dmt[2]; dmt[0] = t0; dmt[1] = t1;   // dst mem in D layout (exact f32)

    // ---- msg1: relu(W1 @ [sm, dm, ef, dt] + b1) ----
    f32x4v h[2];
#pragma unroll
    for (int jt = 0; jt < 2; ++jt) {
        f32x4v b1v = tbl(tb, 0*32 + jt*16 + 4*g + tbo);
        f32x4v w64 = tbl(tb, 1*32 + jt*16 + 4*g + tbo);
        f32x4v w65 = tbl(tb, 2*32 + jt*16 + 4*g + tbo);
        f32x4v w66 = tbl(tb, 3*32 + jt*16 + 4*g + tbo);
        f32x4v c;
#pragma unroll
        for (int i = 0; i < 4; ++i)
            c[i] = b1v[i] + ef.x * w64[i] + ef.y * w65[i] + dtv * w66[i];
        c = MFMA(ldfrag(frg, (jt*2+1)*512 + lane*8 + ob), Bd.s8, c);
        c = MFMA(ldfrag(frg, (jt*2+0)*512 + lane*8 + ob), Bs.s8, c);
#pragma unroll
        for (int i = 0; i < 4; ++i) c[i] = fmaxf(c[i], 0.0f);
        h[jt] = c;
    }
    bf16x8 Bh = relayout_reg(h[0], h[1]);

    // ---- msg2 ----
    f32x4v m[2];
#pragma unroll
    for (int jt = 0; jt < 2; ++jt)
        m[jt] = MFMA(ldfrag(frg, (4+jt)*512 + lane*8 + ob), Bh,
                     tbl(tb, 4*32 + jt*16 + 4*g + tbo));
    bf16x8 Bm = relayout_reg(m[0], m[1]);

    // ---- GRU ----
    f32x4v zz[2], uu[2];
#pragma unroll
    for (int jt = 0; jt < 2; ++jt) {
        f32x4v c = tbl(tb, 5*32 + jt*16 + 4*g + tbo);
        c = MFMA(ldfrag(frg, (7+2*jt)*512 + lane*8 + ob), Bd.s8, c);
        c = MFMA(ldfrag(frg, (6+2*jt)*512 + lane*8 + ob), Bm, c);
#pragma unroll
        for (int i = 0; i < 4; ++i) c[i] = sigf(c[i]);
        zz[jt] = c;
    }
#pragma unroll
    for (int jt = 0; jt < 2; ++jt) {
        f32x4v c = tbl(tb, 6*32 + jt*16 + 4*g + tbo);       // r pre-act
        c = MFMA(ldfrag(frg, (11+2*jt)*512 + lane*8 + ob), Bd.s8, c);
        c = MFMA(ldfrag(frg, (10+2*jt)*512 + lane*8 + ob), Bm, c);
        f32x4v hn = tbl(tb, 7*32 + jt*16 + 4*g + tbo);      // h_n
        hn = MFMA(ldfrag(frg, (14+jt)*512 + lane*8 + ob), Bd.s8, hn);
        f32x4v bin = tbl(tb, 8*32 + jt*16 + 4*g + tbo);
        f32x4v npre;
#pragma unroll
        for (int i = 0; i < 4; ++i) npre[i] = fmaf(sigf(c[i]), hn[i], bin[i]);
        npre = MFMA(ldfrag(frg, (16+jt)*512 + lane*8 + ob), Bm, npre);
#pragma unroll
        for (int i = 0; i < 4; ++i) {
            float n = tanhf_fast(npre[i]);
            uu[jt][i] = n + zz[jt][i] * (dmt[jt][i] - n);
        }
    }
    if (winv == e + 1) {
        f32x4v* orow = (f32x4v*)(out_mem + (size_t)dst * 32);
        orow[g]     = uu[0];
        orow[4 + g] = uu[1];
    }

    // ---- attn (folded) -> emb1 -> emb2 -> cls ----
    f32x4v at[2];
#pragma unroll
    for (int jt = 0; jt < 2; ++jt)
        at[jt] = MFMA(ldfrag(frg, (18+jt)*512 + lane*8 + ob), Bd.s8,
                      tbl(tb, 9*32 + jt*16 + 4*g + tbo));
    bf16x8 Ba = relayout_reg(at[0], at[1]);
    f32x4v e1v[2];
#pragma unroll
    for (int jt = 0; jt < 2; ++jt) {
        f32x4v b  = tbl(tb, 10*32 + jt*16 + 4*g + tbo);
        f32x4v wa = tbl(tb, 11*32 + jt*16 + 4*g + tbo);
        f32x4v wb = tbl(tb, 12*32 + jt*16 + 4*g + tbo);
        f32x4v c;
#pragma unroll
        for (int i = 0; i < 4; ++i) c[i] = b[i] + ef.x * wa[i] + ef.y * wb[i];
        c = MFMA(ldfrag(frg, (20+jt)*512 + lane*8 + ob), Ba, c);
#pragma unroll
        for (int i = 0; i < 4; ++i) c[i] = fmaxf(c[i], 0.0f);
        e1v[jt] = c;
    }
    bf16x8 B1 = relayout_reg(e1v[0], e1v[1]);
    f32x4v e2v[2];
#pragma unroll
    for (int jt = 0; jt < 2; ++jt)
        e2v[jt] = MFMA(ldfrag(frg, (22+jt)*512 + lane*8 + ob), B1,
                       tbl(tb, 13*32 + jt*16 + 4*g + tbo));
    bf16x8 B2 = relayout_reg(e2v[0], e2v[1]);
    float part = 0.0f;
#pragma unroll
    for (int jt = 0; jt < 2; ++jt) {
        f32x4v c = MFMA(ldfrag(frg, (24+jt)*512 + lane*8 + ob), B2,
                        tbl(tb, 14*32 + jt*16 + 4*g + tbo));
        f32x4v w2 = tbl(tb, 15*32 + jt*16 + 4*g + tbo);
#pragma unroll
        for (int i = 0; i < 4; ++i) part = fmaf(fmaxf(c[i], 0.0f), w2[i], part);
    }
    part += __shfl_xor(part, 16);
    part += __shfl_xor(part, 32);
    if (lane < 16) {
        int ee = grp * 16 + eI;
        if (ee < E) probs[ee] = sigf(part + clsb2);
    }
}

__global__ __launch_bounds__(BLK, 8) void tgn_mfma16(
    const int* __restrict__ src_ids, const int* __restrict__ dst_ids,
    const float* __restrict__ edge_feat, const float* __restrict__ delta_t,
    const float* __restrict__ memory, const float* __restrict__ cls_b2,
    const float* __restrict__ WSf, const int* __restrict__ winner,
    float* __restrict__ probs, float* __restrict__ out_mem,
    int E, int N, int ngrp) {
    __shared__ uint4 sbuf[SHARE_U4];
    int bid = blockIdx.x, tid = threadIdx.x;

    if (bid < COPY_BLOCKS) {  // copy workers: non-winner rows -> out_mem
        const f32x4v* m4 = (const f32x4v*)memory;
        f32x4v* o4 = (f32x4v*)out_mem;
        const long S = (long)COPY_BLOCKS * BLK;
        const long total4 = (long)N * 8;
        long i0 = (long)bid * BLK + tid;
        for (; i0 + 3 * S < total4; i0 += 4 * S) {
            long i1 = i0 + S, i2 = i0 + 2 * S, i3 = i0 + 3 * S;
            int w0 = winner[i0 >> 3];
            int w1 = winner[i1 >> 3];
            int w2 = winner[i2 >> 3];
            int w3 = winner[i3 >> 3];
            if (w0 == 0) o4[i0] = m4[i0];
            if (w1 == 0) o4[i1] = m4[i1];
            if (w2 == 0) o4[i2] = m4[i2];
            if (w3 == 0) o4[i3] = m4[i3];
        }
        for (; i0 < total4; i0 += S) {
            if (winner[i0 >> 3] == 0) o4[i0] = m4[i0];
        }
        return;
    }

    {   // stage tables + A-fragments into LDS (shared by 8 waves)
        const uint4* s = (const uint4*)WSf;
        for (int i = tid; i < SHARE_U4; i += BLK) sbuf[i] = s[i];
    }
    __syncthreads();
    const float* tb = (const float*)sbuf;
    const unsigned short* frg = (const unsigned short*)((const float*)sbuf + TB_F32);
    int wv = tid >> 6, lane = tid & 63;
    int eI = lane & 15, g = lane >> 4;
    int ewid = (bid - COPY_BLOCKS) * 8 + wv;
    float clsb2 = cls_b2[0];

#define PREF(P, G) do {                                                              \
    int ee = (G) * 16 + eI; if (ee >= E) ee = E - 1;                                 \
    e##P = ee;                                                                       \
    int sid = src_ids[ee]; dst##P = dst_ids[ee];                                     \
    ef##P = ((const float2*)edge_feat)[ee]; dt##P = delta_t[ee];                     \
    win##P = winner[dst##P];                                                         \
    const f32x4v* sp_ = (const f32x4v*)(memory + (size_t)sid * 32);                  \
    const f32x4v* dp_ = (const f32x4v*)(memory + (size_t)dst##P * 32);               \
    S##P##a = sp_[2*g]; S##P##b = sp_[2*g+1];                                        \
    D##P##a = dp_[2*g]; D##P##b = dp_[2*g+1];                                        \
    T##P##0 = dp_[g];   T##P##1 = dp_[4+g];                                          \
} while (0)

    int g0 = ewid;
    if (g0 < ngrp) {
        int eA, dstA, winA; float2 efA; float dtA;
        f32x4v SAa, SAb, DAa, DAb, TA0, TA1;
        int eB, dstB, winB; float2 efB; float dtB;
        f32x4v SBa, SBb, DBa, DBb, TB0, TB1;
        PREF(A, g0);
        for (;;) {
            int gn = g0 + EDGE_WAVES;
            { int gp = (gn < ngrp) ? gn : (ngrp - 1); PREF(B, gp); }
            asm volatile("" ::: "memory");   // pin: B's loads may not sink below
            compute16(g0, E, eI, g, lane, eA, dstA, winA, efA, dtA,
                      SAa, SAb, DAa, DAb, TA0, TA1,
                      tb, frg, clsb2, probs, out_mem);
            if (gn >= ngrp) break;
            g0 = gn;
            gn = g0 + EDGE_WAVES;
            { int gp = (gn < ngrp) ? gn : (ngrp - 1); PREF(A, gp); }
            asm volatile("" ::: "memory");
            compute16(g0, E, eI, g, lane, eB, dstB, winB, efB, dtB,
                      SBa, SBb, DBa, DBb, TB0, TB1,
                      tb, frg, clsb2, probs, out_mem);
            if (gn >= ngrp) break;
            g0 = gn;
        }
    }
#undef PREF
}

extern "C" void kernel_launch(void* const* d_in, const int* in_sizes, int n_in,
                              void* d_out, int out_size, void* d_ws, size_t ws_size,
                              hipStream_t stream) {
    const int*   src_ids   = (const int*)d_in[0];
    const int*   dst_ids   = (const int*)d_in[1];
    const float* edge_feat = (const float*)d_in[2];
    const float* delta_t   = (const float*)d_in[3];
    const float* memory    = (const float*)d_in[4];
    const float* msg_W1 = (const float*)d_in[5],  *msg_b1 = (const float*)d_in[6];
    const float* msg_W2 = (const float*)d_in[7],  *msg_b2 = (const float*)d_in[8];
    const float* w_ih   = (const float*)d_in[9],  *b_ih   = (const float*)d_in[10];
    const float* w_hh   = (const float*)d_in[11], *b_hh   = (const float*)d_in[12];
    const float* Wv     = (const float*)d_in[13], *bv     = (const float*)d_in[14];
    const float* Wo     = (const float*)d_in[15], *bo     = (const float*)d_in[16];
    const float* emb_W1 = (const float*)d_in[17], *emb_b1 = (const float*)d_in[18];
    const float* emb_W2 = (const float*)d_in[19], *emb_b2 = (const float*)d_in[20];
    const float* cls_W1 = (const float*)d_in[21], *cls_b1 = (const float*)d_in[22];
    const float* cls_W2 = (const float*)d_in[23], *cls_b2 = (const float*)d_in[24];

    int E = in_sizes[0];
    int N = in_sizes[4] / 32;
    int ngrp = (E + 15) / 16;

    int*   winner = (int*)d_ws;
    float* WSf    = (float*)((char*)d_ws + (size_t)N * sizeof(int));
    float* probs  = (float*)d_out;
    float* outmem = probs + E;

    hipMemsetAsync(winner, 0, (size_t)N * sizeof(int), stream);
    winner_k<<<(E + 255) / 256, 256, 0, stream>>>(dst_ids, winner, E);
    prep_k<<<1, 256, 0, stream>>>(msg_W1, msg_b1, msg_W2, msg_b2,
                                  w_ih, b_ih, w_hh, b_hh,
                                  Wv, bv, Wo, bo,
                                  emb_W1, emb_b1, emb_W2, emb_b2,
                                  cls_W1, cls_b1, cls_W2, WSf);
    tgn_mfma16<<<GRID, BLK, 0, stream>>>(src_ids, dst_ids, edge_feat, delta_t,
                                         memory, cls_b2, WSf, winner,
                                         probs, outmem, E, N, ngrp);
}

// Round 12
// 293.765 us; speedup vs baseline: 1.3098x; 1.3098x over previous
//
#include <hip/hip_runtime.h>
#include <hip/hip_bf16.h>

typedef float  f32x4v __attribute__((ext_vector_type(4)));
typedef short  bf16x8 __attribute__((ext_vector_type(8)));

#define NFRAG   26
#define TB_F32  512                            // 16 tables x 32 f32
#define FRG_U16 (NFRAG*512)                    // 26 frags x 64 lanes x 8 bf16
#define SHARE_BYTES (TB_F32*4 + FRG_U16*2)     // 28672 B staged to LDS
#define SHARE_U4 (SHARE_BYTES/16)              // 1792 uint4
#define WC_OFF 7168                            // WC scratch offset in WS floats

#define BLK 256
#define COPY_BLOCKS 256
#define EDGE_BLOCKS 768
#define GRID (COPY_BLOCKS + EDGE_BLOCKS)       // 1024 = 4 blocks/CU resident
#define EDGE_WAVES (EDGE_BLOCKS * 4)           // 3072

#define MFMA(a,b,c) __builtin_amdgcn_mfma_f32_16x16x32_bf16(a,b,c,0,0,0)

__device__ __forceinline__ float sigf(float v) { return 1.0f / (1.0f + __expf(-v)); }
__device__ __forceinline__ float tanhf_fast(float v) {
    float a = fabsf(v);
    float t = __expf(-2.0f * a);
    float r = (1.0f - t) / (1.0f + t);
    return v < 0.0f ? -r : r;
}
__device__ __forceinline__ unsigned pk(float a, float b) {   // bf16(a) lo | bf16(b) hi
    union { __hip_bfloat162 h; unsigned u; } c;
    c.h = __float22bfloat162_rn(make_float2(a, b));
    return c.u;
}

union FragU { uint4 u4; bf16x8 s8; unsigned u[4]; };

__device__ __forceinline__ bf16x8 ldfrag(const unsigned short* frg, int idx_u16) {
    FragU c; c.u4 = *(const uint4*)(frg + idx_u16); return c.s8;
}
__device__ __forceinline__ f32x4v tbl(const float* tb, int idx_f32) {
    return *(const f32x4v*)(tb + idx_f32);
}
// In-register D->B relayout (R9-verified): consumer A-frags are k-permuted so
// the lane's 8 D values ARE its B fragment. Zero cross-lane, zero LDS.
__device__ __forceinline__ bf16x8 relayout_reg(f32x4v h0, f32x4v h1) {
    FragU c;
    c.u[0] = pk(h0[0], h0[1]); c.u[1] = pk(h0[2], h0[3]);
    c.u[2] = pk(h1[0], h1[1]); c.u[3] = pk(h1[2], h1[3]);
    return c.s8;
}

__global__ void winner_k(const int* __restrict__ dst_ids, int* __restrict__ winner, int E) {
    int e = blockIdx.x * 256 + threadIdx.x;
    if (e < E) atomicMax(winner + dst_ids[e], e + 1);
}

__global__ void prep_k(const float* __restrict__ msg_W1, const float* __restrict__ msg_b1,
                       const float* __restrict__ msg_W2, const float* __restrict__ msg_b2,
                       const float* __restrict__ w_ih, const float* __restrict__ b_ih,
                       const float* __restrict__ w_hh, const float* __restrict__ b_hh,
                       const float* __restrict__ Wv, const float* __restrict__ bv,
                       const float* __restrict__ Wo, const float* __restrict__ bo,
                       const float* __restrict__ emb_W1, const float* __restrict__ emb_b1,
                       const float* __restrict__ emb_W2, const float* __restrict__ emb_b2,
                       const float* __restrict__ cls_W1, const float* __restrict__ cls_b1,
                       const float* __restrict__ cls_W2, float* __restrict__ WSf) {
    int t = threadIdx.x;  // one block, 256 threads
    float* tb = WSf;
    unsigned short* frg = (unsigned short*)(WSf + TB_F32);
    float* WC = WSf + WC_OFF;  // [32][32] folded Wo@Wv
    if (t < 32) {
        int j = t;
        tb[0*32+j]  = msg_b1[j];
        tb[1*32+j]  = msg_W1[j*67+64];
        tb[2*32+j]  = msg_W1[j*67+65];
        tb[3*32+j]  = msg_W1[j*67+66];
        tb[4*32+j]  = msg_b2[j];
        tb[5*32+j]  = b_ih[32+j] + b_hh[32+j];     // z bias
        tb[6*32+j]  = b_ih[j] + b_hh[j];           // r bias
        tb[7*32+j]  = b_hh[64+j];                  // h_n bias
        tb[8*32+j]  = b_ih[64+j];                  // i_n bias
        float a = bo[j];
        for (int o = 0; o < 32; ++o) a += Wo[j*32+o] * bv[o];
        tb[9*32+j]  = a;                           // folded attn bias
        tb[10*32+j] = emb_b1[j];
        tb[11*32+j] = emb_W1[j*34+32];
        tb[12*32+j] = emb_W1[j*34+33];
        tb[13*32+j] = emb_b2[j];
        tb[14*32+j] = cls_b1[j];
        tb[15*32+j] = cls_W2[j];
    }
    for (int i = t; i < 1024; i += 256) {
        int j = i >> 5, k = i & 31;
        float a = 0.0f;
        for (int o = 0; o < 32; ++o) a += Wo[j*32+o] * Wv[o*32+k];
        WC[i] = a;
    }
    __syncthreads();
    // A-fragment pack: frag f, lane l, elem i -> W[j0 + (l&15)][k0 + kidx]
    // kidx = kb (natural) or m(kb) for consumers of relayout_reg output.
    for (int idx = t; idx < NFRAG * 512; idx += 256) {
        int f = idx >> 9, l = (idx >> 3) & 63, i = idx & 7;
        int r = l & 15, kb = ((l >> 4) << 3) + i;
        const float* P; int j0 = 0, k0 = 0, ld = 32;
        bool mapped = false;
        switch (f) {
            case 0:  P = msg_W1; j0 = 0;  k0 = 0;  ld = 67; break;
            case 1:  P = msg_W1; j0 = 0;  k0 = 32; ld = 67; break;
            case 2:  P = msg_W1; j0 = 16; k0 = 0;  ld = 67; break;
            case 3:  P = msg_W1; j0 = 16; k0 = 32; ld = 67; break;
            case 4:  P = msg_W2; j0 = 0;  mapped = true; break;
            case 5:  P = msg_W2; j0 = 16; mapped = true; break;
            case 6:  P = w_ih;   j0 = 32; mapped = true; break;   // z ih
            case 7:  P = w_hh;   j0 = 32; break;                  // z hh
            case 8:  P = w_ih;   j0 = 48; mapped = true; break;
            case 9:  P = w_hh;   j0 = 48; break;
            case 10: P = w_ih;   j0 = 0;  mapped = true; break;   // r ih
            case 11: P = w_hh;   j0 = 0;  break;
            case 12: P = w_ih;   j0 = 16; mapped = true; break;
            case 13: P = w_hh;   j0 = 16; break;
            case 14: P = w_hh;   j0 = 64; break;                  // n hh
            case 15: P = w_hh;   j0 = 80; break;
            case 16: P = w_ih;   j0 = 64; mapped = true; break;   // n ih
            case 17: P = w_ih;   j0 = 80; mapped = true; break;
            case 18: P = WC;     j0 = 0;  break;                  // folded attn
            case 19: P = WC;     j0 = 16; break;
            case 20: P = emb_W1; j0 = 0;  ld = 34; mapped = true; break;
            case 21: P = emb_W1; j0 = 16; ld = 34; mapped = true; break;
            case 22: P = emb_W2; j0 = 0;  mapped = true; break;
            case 23: P = emb_W2; j0 = 16; mapped = true; break;
            case 24: P = cls_W1; j0 = 0;  mapped = true; break;
            default: P = cls_W1; j0 = 16; mapped = true; break;
        }
        int kidx = kb;
        if (mapped) kidx = 16 * ((kb >> 2) & 1) + 4 * (kb >> 3) + (kb & 3);
        __hip_bfloat16 hv = __float2bfloat16(P[(j0 + r) * ld + k0 + kidx]);
        frg[idx] = *(unsigned short*)&hv;
    }
}

__device__ __forceinline__ void compute16(
    int grp, int E, int eI, int g, int lane,
    int e, int dst, int winv, float2 ef, float dtv,
    f32x4v sa, f32x4v sb, f32x4v da, f32x4v db, f32x4v t0, f32x4v t1,
    const float* tb, const unsigned short* frg, float clsb2,
    float* __restrict__ probs, float* __restrict__ out_mem) {
    int ob = 0, tbo = 0;
    asm volatile("" : "+v"(ob), "+v"(tbo));  // block LICM of LDS frag/table reads

    FragU Bs, Bd;
    Bs.u[0] = pk(sa[0], sa[1]); Bs.u[1] = pk(sa[2], sa[3]);
    Bs.u[2] = pk(sb[0], sb[1]); Bs.u[3] = pk(sb[2], sb[3]);
    Bd.u[0] = pk(da[0], da[1]); Bd.u[1] = pk(da[2], da[3]);
    Bd.u[2] = pk(db[0], db[1]); Bd.u[3] = pk(db[2], db[3]);
    f32x4v dmt[2]; dmt[0] = t0; dmt[1] = t1;   // dst mem in D layout (exact f32)

    // ---- msg1: relu(W1 @ [sm, dm, ef, dt] + b1) ----
    f32x4v h[2];
#pragma unroll
    for (int jt = 0; jt < 2; ++jt) {
        f32x4v b1v = tbl(tb, 0*32 + jt*16 + 4*g + tbo);
        f32x4v w64 = tbl(tb, 1*32 + jt*16 + 4*g + tbo);
        f32x4v w65 = tbl(tb, 2*32 + jt*16 + 4*g + tbo);
        f32x4v w66 = tbl(tb, 3*32 + jt*16 + 4*g + tbo);
        f32x4v c;
#pragma unroll
        for (int i = 0; i < 4; ++i)
            c[i] = b1v[i] + ef.x * w64[i] + ef.y * w65[i] + dtv * w66[i];
        c = MFMA(ldfrag(frg, (jt*2+1)*512 + lane*8 + ob), Bd.s8, c);
        c = MFMA(ldfrag(frg, (jt*2+0)*512 + lane*8 + ob), Bs.s8, c);
#pragma unroll
        for (int i = 0; i < 4; ++i) c[i] = fmaxf(c[i], 0.0f);
        h[jt] = c;
    }
    bf16x8 Bh = relayout_reg(h[0], h[1]);

    // ---- msg2 ----
    f32x4v m[2];
#pragma unroll
    for (int jt = 0; jt < 2; ++jt)
        m[jt] = MFMA(ldfrag(frg, (4+jt)*512 + lane*8 + ob), Bh,
                     tbl(tb, 4*32 + jt*16 + 4*g + tbo));
    bf16x8 Bm = relayout_reg(m[0], m[1]);

    // ---- GRU ----
    f32x4v zz[2], uu[2];
#pragma unroll
    for (int jt = 0; jt < 2; ++jt) {
        f32x4v c = tbl(tb, 5*32 + jt*16 + 4*g + tbo);
        c = MFMA(ldfrag(frg, (7+2*jt)*512 + lane*8 + ob), Bd.s8, c);
        c = MFMA(ldfrag(frg, (6+2*jt)*512 + lane*8 + ob), Bm, c);
#pragma unroll
        for (int i = 0; i < 4; ++i) c[i] = sigf(c[i]);
        zz[jt] = c;
    }
#pragma unroll
    for (int jt = 0; jt < 2; ++jt) {
        f32x4v c = tbl(tb, 6*32 + jt*16 + 4*g + tbo);       // r pre-act
        c = MFMA(ldfrag(frg, (11+2*jt)*512 + lane*8 + ob), Bd.s8, c);
        c = MFMA(ldfrag(frg, (10+2*jt)*512 + lane*8 + ob), Bm, c);
        f32x4v hn = tbl(tb, 7*32 + jt*16 + 4*g + tbo);      // h_n
        hn = MFMA(ldfrag(frg, (14+jt)*512 + lane*8 + ob), Bd.s8, hn);
        f32x4v bin = tbl(tb, 8*32 + jt*16 + 4*g + tbo);
        f32x4v npre;
#pragma unroll
        for (int i = 0; i < 4; ++i) npre[i] = fmaf(sigf(c[i]), hn[i], bin[i]);
        npre = MFMA(ldfrag(frg, (16+jt)*512 + lane*8 + ob), Bm, npre);
#pragma unroll
        for (int i = 0; i < 4; ++i) {
            float n = tanhf_fast(npre[i]);
            uu[jt][i] = n + zz[jt][i] * (dmt[jt][i] - n);
        }
    }
    if (winv == e + 1) {
        f32x4v* orow = (f32x4v*)(out_mem + (size_t)dst * 32);
        orow[g]     = uu[0];
        orow[4 + g] = uu[1];
    }

    // ---- attn (folded) -> emb1 -> emb2 -> cls ----
    f32x4v at[2];
#pragma unroll
    for (int jt = 0; jt < 2; ++jt)
        at[jt] = MFMA(ldfrag(frg, (18+jt)*512 + lane*8 + ob), Bd.s8,
                      tbl(tb, 9*32 + jt*16 + 4*g + tbo));
    bf16x8 Ba = relayout_reg(at[0], at[1]);
    f32x4v e1v[2];
#pragma unroll
    for (int jt = 0; jt < 2; ++jt) {
        f32x4v b  = tbl(tb, 10*32 + jt*16 + 4*g + tbo);
        f32x4v wa = tbl(tb, 11*32 + jt*16 + 4*g + tbo);
        f32x4v wb = tbl(tb, 12*32 + jt*16 + 4*g + tbo);
        f32x4v c;
#pragma unroll
        for (int i = 0; i < 4; ++i) c[i] = b[i] + ef.x * wa[i] + ef.y * wb[i];
        c = MFMA(ldfrag(frg, (20+jt)*512 + lane*8 + ob), Ba, c);
#pragma unroll
        for (int i = 0; i < 4; ++i) c[i] = fmaxf(c[i], 0.0f);
        e1v[jt] = c;
    }
    bf16x8 B1 = relayout_reg(e1v[0], e1v[1]);
    f32x4v e2v[2];
#pragma unroll
    for (int jt = 0; jt < 2; ++jt)
        e2v[jt] = MFMA(ldfrag(frg, (22+jt)*512 + lane*8 + ob), B1,
                       tbl(tb, 13*32 + jt*16 + 4*g + tbo));
    bf16x8 B2 = relayout_reg(e2v[0], e2v[1]);
    float part = 0.0f;
#pragma unroll
    for (int jt = 0; jt < 2; ++jt) {
        f32x4v c = MFMA(ldfrag(frg, (24+jt)*512 + lane*8 + ob), B2,
                        tbl(tb, 14*32 + jt*16 + 4*g + tbo));
        f32x4v w2 = tbl(tb, 15*32 + jt*16 + 4*g + tbo);
#pragma unroll
        for (int i = 0; i < 4; ++i) part = fmaf(fmaxf(c[i], 0.0f), w2[i], part);
    }
    part += __shfl_xor(part, 16);
    part += __shfl_xor(part, 32);
    if (lane < 16) {
        int ee = grp * 16 + eI;
        if (ee < E) probs[ee] = sigf(part + clsb2);
    }
}

__global__ __launch_bounds__(BLK, 4) void tgn_mfma16(
    const int* __restrict__ src_ids, const int* __restrict__ dst_ids,
    const float* __restrict__ edge_feat, const float* __restrict__ delta_t,
    const float* __restrict__ memory, const float* __restrict__ cls_b2,
    const float* __restrict__ WSf, const int* __restrict__ winner,
    float* __restrict__ probs, float* __restrict__ out_mem,
    int E, int N, int ngrp) {
    __shared__ uint4 sbuf[SHARE_U4];
    int bid = blockIdx.x, tid = threadIdx.x;

    if (bid < COPY_BLOCKS) {  // copy workers: non-winner rows -> out_mem
        const f32x4v* m4 = (const f32x4v*)memory;
        f32x4v* o4 = (f32x4v*)out_mem;
        const long S = (long)COPY_BLOCKS * BLK;
        const long total4 = (long)N * 8;
        long i0 = (long)bid * BLK + tid;
        for (; i0 + 3 * S < total4; i0 += 4 * S) {
            long i1 = i0 + S, i2 = i0 + 2 * S, i3 = i0 + 3 * S;
            int w0 = winner[i0 >> 3];
            int w1 = winner[i1 >> 3];
            int w2 = winner[i2 >> 3];
            int w3 = winner[i3 >> 3];
            if (w0 == 0) o4[i0] = m4[i0];
            if (w1 == 0) o4[i1] = m4[i1];
            if (w2 == 0) o4[i2] = m4[i2];
            if (w3 == 0) o4[i3] = m4[i3];
        }
        for (; i0 < total4; i0 += S) {
            if (winner[i0 >> 3] == 0) o4[i0] = m4[i0];
        }
        return;
    }

    {   // stage tables + A-fragments into LDS
        const uint4* s = (const uint4*)WSf;
        for (int i = tid; i < SHARE_U4; i += BLK) sbuf[i] = s[i];
    }
    __syncthreads();
    const float* tb = (const float*)sbuf;
    const unsigned short* frg = (const unsigned short*)((const float*)sbuf + TB_F32);
    int wv = tid >> 6, lane = tid & 63;
    int eI = lane & 15, g = lane >> 4;
    int ewid = (bid - COPY_BLOCKS) * 4 + wv;
    float clsb2 = cls_b2[0];

#define PREF(P, G) do {                                                              \
    int ee = (G) * 16 + eI; if (ee >= E) ee = E - 1;                                 \
    e##P = ee;                                                                       \
    int sid = src_ids[ee]; dst##P = dst_ids[ee];                                     \
    ef##P = ((const float2*)edge_feat)[ee]; dt##P = delta_t[ee];                     \
    win##P = winner[dst##P];                                                         \
    const f32x4v* sp_ = (const f32x4v*)(memory + (size_t)sid * 32);                  \
    const f32x4v* dp_ = (const f32x4v*)(memory + (size_t)dst##P * 32);               \
    S##P##a = sp_[2*g]; S##P##b = sp_[2*g+1];                                        \
    D##P##a = dp_[2*g]; D##P##b = dp_[2*g+1];                                        \
    T##P##0 = dp_[g];   T##P##1 = dp_[4+g];                                          \
} while (0)

// Force the prefetched state to be materialized in VGPRs HERE (not sunk).
#define PIN(P) asm volatile("" : "+v"(S##P##a), "+v"(S##P##b), "+v"(D##P##a),        \
                                 "+v"(D##P##b), "+v"(T##P##0), "+v"(T##P##1),        \
                                 "+v"(win##P), "+v"(dt##P))

    int g0 = ewid;
    if (g0 < ngrp) {
        int eA, dstA, winA; float2 efA; float dtA;
        f32x4v SAa, SAb, DAa, DAb, TA0, TA1;
        int eB, dstB, winB; float2 efB; float dtB;
        f32x4v SBa, SBb, DBa, DBb, TB0, TB1;
        PREF(A, g0);
        for (;;) {
            int gn = g0 + EDGE_WAVES;
            { int gp = (gn < ngrp) ? gn : (ngrp - 1); PREF(B, gp); PIN(B); }
            compute16(g0, E, eI, g, lane, eA, dstA, winA, efA, dtA,
                      SAa, SAb, DAa, DAb, TA0, TA1,
                      tb, frg, clsb2, probs, out_mem);
            if (gn >= ngrp) break;
            g0 = gn;
            gn = g0 + EDGE_WAVES;
            { int gp = (gn < ngrp) ? gn : (ngrp - 1); PREF(A, gp); PIN(A); }
            compute16(g0, E, eI, g, lane, eB, dstB, winB, efB, dtB,
                      SBa, SBb, DBa, DBb, TB0, TB1,
                      tb, frg, clsb2, probs, out_mem);
            if (gn >= ngrp) break;
            g0 = gn;
        }
    }
#undef PREF
#undef PIN
}

extern "C" void kernel_launch(void* const* d_in, const int* in_sizes, int n_in,
                              void* d_out, int out_size, void* d_ws, size_t ws_size,
                              hipStream_t stream) {
    const int*   src_ids   = (const int*)d_in[0];
    const int*   dst_ids   = (const int*)d_in[1];
    const float* edge_feat = (const float*)d_in[2];
    const float* delta_t   = (const float*)d_in[3];
    const float* memory    = (const float*)d_in[4];
    const float* msg_W1 = (const float*)d_in[5],  *msg_b1 = (const float*)d_in[6];
    const float* msg_W2 = (const float*)d_in[7],  *msg_b2 = (const float*)d_in[8];
    const float* w_ih   = (const float*)d_in[9],  *b_ih   = (const float*)d_in[10];
    const float* w_hh   = (const float*)d_in[11], *b_hh   = (const float*)d_in[12];
    const float* Wv     = (const float*)d_in[13], *bv     = (const float*)d_in[14];
    const float* Wo     = (const float*)d_in[15], *bo     = (const float*)d_in[16];
    const float* emb_W1 = (const float*)d_in[17], *emb_b1 = (const float*)d_in[18];
    const float* emb_W2 = (const float*)d_in[19], *emb_b2 = (const float*)d_in[20];
    const float* cls_W1 = (const float*)d_in[21], *cls_b1 = (const float*)d_in[22];
    const float* cls_W2 = (const float*)d_in[23], *cls_b2 = (const float*)d_in[24];

    int E = in_sizes[0];
    int N = in_sizes[4] / 32;
    int ngrp = (E + 15) / 16;

    int*   winner = (int*)d_ws;
    float* WSf    = (float*)((char*)d_ws + (size_t)N * sizeof(int));
    float* probs  = (float*)d_out;
    float* outmem = probs + E;

    hipMemsetAsync(winner, 0, (size_t)N * sizeof(int), stream);
    winner_k<<<(E + 255) / 256, 256, 0, stream>>>(dst_ids, winner, E);
    prep_k<<<1, 256, 0, stream>>>(msg_W1, msg_b1, msg_W2, msg_b2,
                                  w_ih, b_ih, w_hh, b_hh,
                                  Wv, bv, Wo, bo,
                                  emb_W1, emb_b1, emb_W2, emb_b2,
                                  cls_W1, cls_b1, cls_W2, WSf);
    tgn_mfma16<<<GRID, BLK, 0, stream>>>(src_ids, dst_ids, edge_feat, delta_t,
                                         memory, cls_b2, WSf, winner,
                                         probs, outmem, E, N, ngrp);
}

// Round 13
// 292.534 us; speedup vs baseline: 1.3153x; 1.0042x over previous
//
#include <hip/hip_runtime.h>
#include <hip/hip_bf16.h>

typedef float  f32x4v __attribute__((ext_vector_type(4)));
typedef float  f32x2v __attribute__((ext_vector_type(2)));
typedef short  bf16x8 __attribute__((ext_vector_type(8)));

#define NFRAG   26
#define TB_F32  512                            // 16 tables x 32 f32
#define FRG_U16 (NFRAG*512)                    // 26 frags x 64 lanes x 8 bf16
#define SHARE_BYTES (TB_F32*4 + FRG_U16*2)     // 28672 B staged to LDS
#define SHARE_U4 (SHARE_BYTES/16)              // 1792 uint4
#define WC_OFF 7168                            // WC scratch offset in WS floats (dead after prep)

#define BLK 256
#define COPY_BLOCKS 256
#define EDGE_BLOCKS 768
#define GRID (COPY_BLOCKS + EDGE_BLOCKS)       // 1024 = 4 blocks/CU resident
#define EDGE_WAVES (EDGE_BLOCKS * 4)           // 3072

#define MFMA(a,b,c) __builtin_amdgcn_mfma_f32_16x16x32_bf16(a,b,c,0,0,0)

__device__ __forceinline__ float sigf(float v) { return 1.0f / (1.0f + __expf(-v)); }
__device__ __forceinline__ float tanhf_fast(float v) {
    float a = fabsf(v);
    float t = __expf(-2.0f * a);
    float r = (1.0f - t) / (1.0f + t);
    return v < 0.0f ? -r : r;
}
__device__ __forceinline__ unsigned pk(float a, float b) {   // bf16(a) lo | bf16(b) hi
    union { __hip_bfloat162 h; unsigned u; } c;
    c.h = __float22bfloat162_rn(make_float2(a, b));
    return c.u;
}

union FragU { uint4 u4; bf16x8 s8; unsigned u[4]; };

__device__ __forceinline__ bf16x8 ldfrag(const unsigned short* frg, int idx_u16) {
    FragU c; c.u4 = *(const uint4*)(frg + idx_u16); return c.s8;
}
__device__ __forceinline__ f32x4v tbl(const float* tb, int idx_f32) {
    return *(const f32x4v*)(tb + idx_f32);
}
__device__ __forceinline__ bf16x8 relayout_reg(f32x4v h0, f32x4v h1) {
    FragU c;
    c.u[0] = pk(h0[0], h0[1]); c.u[1] = pk(h0[2], h0[3]);
    c.u[2] = pk(h1[0], h1[1]); c.u[3] = pk(h1[2], h1[3]);
    return c.s8;
}

__global__ void winner_k(const int* __restrict__ dst_ids, int* __restrict__ winner, int E) {
    int e = blockIdx.x * 256 + threadIdx.x;
    if (e < E) atomicMax(winner + dst_ids[e], e + 1);
}

__global__ void prep_k(const float* __restrict__ msg_W1, const float* __restrict__ msg_b1,
                       const float* __restrict__ msg_W2, const float* __restrict__ msg_b2,
                       const float* __restrict__ w_ih, const float* __restrict__ b_ih,
                       const float* __restrict__ w_hh, const float* __restrict__ b_hh,
                       const float* __restrict__ Wv, const float* __restrict__ bv,
                       const float* __restrict__ Wo, const float* __restrict__ bo,
                       const float* __restrict__ emb_W1, const float* __restrict__ emb_b1,
                       const float* __restrict__ emb_W2, const float* __restrict__ emb_b2,
                       const float* __restrict__ cls_W1, const float* __restrict__ cls_b1,
                       const float* __restrict__ cls_W2, float* __restrict__ WSf) {
    int t = threadIdx.x;  // one block, 256 threads
    float* tb = WSf;
    unsigned short* frg = (unsigned short*)(WSf + TB_F32);
    float* WC = WSf + WC_OFF;  // [32][32] folded Wo@Wv (dead after this kernel)
    if (t < 32) {
        int j = t;
        tb[0*32+j]  = msg_b1[j];
        tb[1*32+j]  = msg_W1[j*67+64];
        tb[2*32+j]  = msg_W1[j*67+65];
        tb[3*32+j]  = msg_W1[j*67+66];
        tb[4*32+j]  = msg_b2[j];
        tb[5*32+j]  = b_ih[32+j] + b_hh[32+j];     // z bias
        tb[6*32+j]  = b_ih[j] + b_hh[j];           // r bias
        tb[7*32+j]  = b_hh[64+j];                  // h_n bias
        tb[8*32+j]  = b_ih[64+j];                  // i_n bias
        float a = bo[j];
        for (int o = 0; o < 32; ++o) a += Wo[j*32+o] * bv[o];
        tb[9*32+j]  = a;                           // folded attn bias
        tb[10*32+j] = emb_b1[j];
        tb[11*32+j] = emb_W1[j*34+32];
        tb[12*32+j] = emb_W1[j*34+33];
        tb[13*32+j] = emb_b2[j];
        tb[14*32+j] = cls_b1[j];
        tb[15*32+j] = cls_W2[j];
    }
    for (int i = t; i < 1024; i += 256) {
        int j = i >> 5, k = i & 31;
        float a = 0.0f;
        for (int o = 0; o < 32; ++o) a += Wo[j*32+o] * Wv[o*32+k];
        WC[i] = a;
    }
    __syncthreads();
    for (int idx = t; idx < NFRAG * 512; idx += 256) {
        int f = idx >> 9, l = (idx >> 3) & 63, i = idx & 7;
        int r = l & 15, kb = ((l >> 4) << 3) + i;
        const float* P; int j0 = 0, k0 = 0, ld = 32;
        bool mapped = false;
        switch (f) {
            case 0:  P = msg_W1; j0 = 0;  k0 = 0;  ld = 67; break;
            case 1:  P = msg_W1; j0 = 0;  k0 = 32; ld = 67; break;
            case 2:  P = msg_W1; j0 = 16; k0 = 0;  ld = 67; break;
            case 3:  P = msg_W1; j0 = 16; k0 = 32; ld = 67; break;
            case 4:  P = msg_W2; j0 = 0;  mapped = true; break;
            case 5:  P = msg_W2; j0 = 16; mapped = true; break;
            case 6:  P = w_ih;   j0 = 32; mapped = true; break;   // z ih
            case 7:  P = w_hh;   j0 = 32; break;                  // z hh
            case 8:  P = w_ih;   j0 = 48; mapped = true; break;
            case 9:  P = w_hh;   j0 = 48; break;
            case 10: P = w_ih;   j0 = 0;  mapped = true; break;   // r ih
            case 11: P = w_hh;   j0 = 0;  break;
            case 12: P = w_ih;   j0 = 16; mapped = true; break;
            case 13: P = w_hh;   j0 = 16; break;
            case 14: P = w_hh;   j0 = 64; break;                  // n hh
            case 15: P = w_hh;   j0 = 80; break;
            case 16: P = w_ih;   j0 = 64; mapped = true; break;   // n ih
            case 17: P = w_ih;   j0 = 80; mapped = true; break;
            case 18: P = WC;     j0 = 0;  break;                  // folded attn
            case 19: P = WC;     j0 = 16; break;
            case 20: P = emb_W1; j0 = 0;  ld = 34; mapped = true; break;
            case 21: P = emb_W1; j0 = 16; ld = 34; mapped = true; break;
            case 22: P = emb_W2; j0 = 0;  mapped = true; break;
            case 23: P = emb_W2; j0 = 16; mapped = true; break;
            case 24: P = cls_W1; j0 = 0;  mapped = true; break;
            default: P = cls_W1; j0 = 16; mapped = true; break;
        }
        int kidx = kb;
        if (mapped) kidx = 16 * ((kb >> 2) & 1) + 4 * (kb >> 3) + (kb & 3);
        __hip_bfloat16 hv = __float2bfloat16(P[(j0 + r) * ld + k0 + kidx]);
        frg[idx] = *(unsigned short*)&hv;
    }
}

__device__ __forceinline__ void compute16(
    int grp, int E, int eI, int g, int lane,
    int e, int dst, int winv, f32x2v ef, float dtv,
    f32x4v sa, f32x4v sb, f32x4v da, f32x4v db, f32x4v t0, f32x4v t1,
    const float* tb, const unsigned short* frg, float clsb2,
    float* __restrict__ probs, float* __restrict__ out_mem, float* trash) {
    int ob = 0, tbo = 0;
    asm volatile("" : "+v"(ob), "+v"(tbo));  // block LICM of LDS frag/table reads

    FragU Bs, Bd;
    Bs.u[0] = pk(sa[0], sa[1]); Bs.u[1] = pk(sa[2], sa[3]);
    Bs.u[2] = pk(sb[0], sb[1]); Bs.u[3] = pk(sb[2], sb[3]);
    Bd.u[0] = pk(da[0], da[1]); Bd.u[1] = pk(da[2], da[3]);
    Bd.u[2] = pk(db[0], db[1]); Bd.u[3] = pk(db[2], db[3]);
    f32x4v dmt[2]; dmt[0] = t0; dmt[1] = t1;   // dst mem in D layout (exact f32)

    // ---- msg1: relu(W1 @ [sm, dm, ef, dt] + b1) ----
    f32x4v h[2];
#pragma unroll
    for (int jt = 0; jt < 2; ++jt) {
        f32x4v b1v = tbl(tb, 0*32 + jt*16 + 4*g + tbo);
        f32x4v w64 = tbl(tb, 1*32 + jt*16 + 4*g + tbo);
        f32x4v w65 = tbl(tb, 2*32 + jt*16 + 4*g + tbo);
        f32x4v w66 = tbl(tb, 3*32 + jt*16 + 4*g + tbo);
        f32x4v c;
#pragma unroll
        for (int i = 0; i < 4; ++i)
            c[i] = b1v[i] + ef[0] * w64[i] + ef[1] * w65[i] + dtv * w66[i];
        c = MFMA(ldfrag(frg, (jt*2+1)*512 + lane*8 + ob), Bd.s8, c);
        c = MFMA(ldfrag(frg, (jt*2+0)*512 + lane*8 + ob), Bs.s8, c);
#pragma unroll
        for (int i = 0; i < 4; ++i) c[i] = fmaxf(c[i], 0.0f);
        h[jt] = c;
    }
    bf16x8 Bh = relayout_reg(h[0], h[1]);

    // ---- msg2 ----
    f32x4v m[2];
#pragma unroll
    for (int jt = 0; jt < 2; ++jt)
        m[jt] = MFMA(ldfrag(frg, (4+jt)*512 + lane*8 + ob), Bh,
                     tbl(tb, 4*32 + jt*16 + 4*g + tbo));
    bf16x8 Bm = relayout_reg(m[0], m[1]);

    // ---- GRU ----
    f32x4v zz[2], uu[2];
#pragma unroll
    for (int jt = 0; jt < 2; ++jt) {
        f32x4v c = tbl(tb, 5*32 + jt*16 + 4*g + tbo);
        c = MFMA(ldfrag(frg, (7+2*jt)*512 + lane*8 + ob), Bd.s8, c);
        c = MFMA(ldfrag(frg, (6+2*jt)*512 + lane*8 + ob), Bm, c);
#pragma unroll
        for (int i = 0; i < 4; ++i) c[i] = sigf(c[i]);
        zz[jt] = c;
    }
#pragma unroll
    for (int jt = 0; jt < 2; ++jt) {
        f32x4v c = tbl(tb, 6*32 + jt*16 + 4*g + tbo);       // r pre-act
        c = MFMA(ldfrag(frg, (11+2*jt)*512 + lane*8 + ob), Bd.s8, c);
        c = MFMA(ldfrag(frg, (10+2*jt)*512 + lane*8 + ob), Bm, c);
        f32x4v hn = tbl(tb, 7*32 + jt*16 + 4*g + tbo);      // h_n
        hn = MFMA(ldfrag(frg, (14+jt)*512 + lane*8 + ob), Bd.s8, hn);
        f32x4v bin = tbl(tb, 8*32 + jt*16 + 4*g + tbo);
        f32x4v npre;
#pragma unroll
        for (int i = 0; i < 4; ++i) npre[i] = fmaf(sigf(c[i]), hn[i], bin[i]);
        npre = MFMA(ldfrag(frg, (16+jt)*512 + lane*8 + ob), Bm, npre);
#pragma unroll
        for (int i = 0; i < 4; ++i) {
            float n = tanhf_fast(npre[i]);
            uu[jt][i] = n + zz[jt][i] * (dmt[jt][i] - n);
        }
    }
    {   // unconditional 2-store winner write (losers hit a trash slot) so the
        // per-group VMEM store count is EXACTLY 2 here (+1 probs below) — the
        // pipeline's s_waitcnt vmcnt(3) depends on this.
        bool w = (winv == e + 1);
        f32x4v* orow = (f32x4v*)(out_mem + (size_t)dst * 32);
        f32x4v* tr   = (f32x4v*)trash;
        f32x4v* p0 = w ? orow + g     : tr + g;
        f32x4v* p1 = w ? orow + 4 + g : tr + 4 + g;
        *p0 = uu[0];
        *p1 = uu[1];
    }

    // ---- attn (folded) -> emb1 -> emb2 -> cls ----
    f32x4v at[2];
#pragma unroll
    for (int jt = 0; jt < 2; ++jt)
        at[jt] = MFMA(ldfrag(frg, (18+jt)*512 + lane*8 + ob), Bd.s8,
                      tbl(tb, 9*32 + jt*16 + 4*g + tbo));
    bf16x8 Ba = relayout_reg(at[0], at[1]);
    f32x4v e1v[2];
#pragma unroll
    for (int jt = 0; jt < 2; ++jt) {
        f32x4v b  = tbl(tb, 10*32 + jt*16 + 4*g + tbo);
        f32x4v wa = tbl(tb, 11*32 + jt*16 + 4*g + tbo);
        f32x4v wb = tbl(tb, 12*32 + jt*16 + 4*g + tbo);
        f32x4v c;
#pragma unroll
        for (int i = 0; i < 4; ++i) c[i] = b[i] + ef[0] * wa[i] + ef[1] * wb[i];
        c = MFMA(ldfrag(frg, (20+jt)*512 + lane*8 + ob), Ba, c);
#pragma unroll
        for (int i = 0; i < 4; ++i) c[i] = fmaxf(c[i], 0.0f);
        e1v[jt] = c;
    }
    bf16x8 B1 = relayout_reg(e1v[0], e1v[1]);
    f32x4v e2v[2];
#pragma unroll
    for (int jt = 0; jt < 2; ++jt)
        e2v[jt] = MFMA(ldfrag(frg, (22+jt)*512 + lane*8 + ob), B1,
                       tbl(tb, 13*32 + jt*16 + 4*g + tbo));
    bf16x8 B2 = relayout_reg(e2v[0], e2v[1]);
    float part = 0.0f;
#pragma unroll
    for (int jt = 0; jt < 2; ++jt) {
        f32x4v c = MFMA(ldfrag(frg, (24+jt)*512 + lane*8 + ob), B2,
                        tbl(tb, 14*32 + jt*16 + 4*g + tbo));
        f32x4v w2 = tbl(tb, 15*32 + jt*16 + 4*g + tbo);
#pragma unroll
        for (int i = 0; i < 4; ++i) part = fmaf(fmaxf(c[i], 0.0f), w2[i], part);
    }
    part += __shfl_xor(part, 16);
    part += __shfl_xor(part, 32);
    if (lane < 16) {   // exec never empty -> exactly 1 store issued
        int ee = grp * 16 + eI;
        if (ee < E) probs[ee] = sigf(part + clsb2);
    }
}

__global__ __launch_bounds__(BLK, 4) void tgn_mfma16(
    const int* __restrict__ src_ids, const int* __restrict__ dst_ids,
    const float* __restrict__ edge_feat, const float* __restrict__ delta_t,
    const float* __restrict__ memory, const float* __restrict__ cls_b2,
    const float* __restrict__ WSf, const int* __restrict__ winner,
    float* __restrict__ probs, float* __restrict__ out_mem, float* trashbase,
    int E, int N, int ngrp) {
    __shared__ uint4 sbuf[SHARE_U4];
    int bid = blockIdx.x, tid = threadIdx.x;

    if (bid < COPY_BLOCKS) {  // copy workers: non-winner rows -> out_mem
        const f32x4v* m4 = (const f32x4v*)memory;
        f32x4v* o4 = (f32x4v*)out_mem;
        const long S = (long)COPY_BLOCKS * BLK;
        const long total4 = (long)N * 8;
        long i0 = (long)bid * BLK + tid;
        for (; i0 + 3 * S < total4; i0 += 4 * S) {
            long i1 = i0 + S, i2 = i0 + 2 * S, i3 = i0 + 3 * S;
            int w0 = winner[i0 >> 3];
            int w1 = winner[i1 >> 3];
            int w2 = winner[i2 >> 3];
            int w3 = winner[i3 >> 3];
            if (w0 == 0) o4[i0] = m4[i0];
            if (w1 == 0) o4[i1] = m4[i1];
            if (w2 == 0) o4[i2] = m4[i2];
            if (w3 == 0) o4[i3] = m4[i3];
        }
        for (; i0 < total4; i0 += S) {
            if (winner[i0 >> 3] == 0) o4[i0] = m4[i0];
        }
        return;
    }

    {   // stage tables + A-fragments into LDS
        const uint4* s = (const uint4*)WSf;
        for (int i = tid; i < SHARE_U4; i += BLK) sbuf[i] = s[i];
    }
    __syncthreads();
    const float* tb = (const float*)sbuf;
    const unsigned short* frg = (const unsigned short*)((const float*)sbuf + TB_F32);
    int wv = tid >> 6, lane = tid & 63;
    int eI = lane & 15, g = lane >> 4;
    int ewid = (bid - COPY_BLOCKS) * 4 + wv;
    float clsb2 = cls_b2[0];
    float* trash = trashbase + (((bid - COPY_BLOCKS) * 4 + wv) & 31) * 32;

// ---- async prefetch machinery (raw asm loads; never sunk, never early-waited) ----
#define IDS_ASM(P, G) do {                                                           \
    int ee_ = (G) * 16 + eI; if (ee_ >= E) ee_ = E - 1;                              \
    e##P = ee_;                                                                      \
    asm volatile("global_load_dword %0, %1, off"                                     \
                 : "=v"(sid##P) : "v"((unsigned long long)(src_ids + ee_)));         \
    asm volatile("global_load_dword %0, %1, off"                                     \
                 : "=v"(dst##P) : "v"((unsigned long long)(dst_ids + ee_)));         \
    asm volatile("global_load_dwordx2 %0, %1, off"                                   \
                 : "=v"(ef##P) : "v"((unsigned long long)(edge_feat + 2*(size_t)ee_)));\
    asm volatile("global_load_dword %0, %1, off"                                     \
                 : "=v"(dt##P) : "v"((unsigned long long)(delta_t + ee_)));          \
} while (0)

#define ROWS_ASM(P) do {                                                             \
    unsigned long long sb_ = (unsigned long long)(memory + (size_t)sid##P * 32);     \
    unsigned long long db_ = (unsigned long long)(memory + (size_t)dst##P * 32);     \
    asm volatile("global_load_dwordx4 %0, %1, off" : "=v"(S##P##a) : "v"(sb_ + 32ull*g));      \
    asm volatile("global_load_dwordx4 %0, %1, off" : "=v"(S##P##b) : "v"(sb_ + 32ull*g + 16)); \
    asm volatile("global_load_dwordx4 %0, %1, off" : "=v"(D##P##a) : "v"(db_ + 32ull*g));      \
    asm volatile("global_load_dwordx4 %0, %1, off" : "=v"(D##P##b) : "v"(db_ + 32ull*g + 16)); \
    asm volatile("global_load_dwordx4 %0, %1, off" : "=v"(T##P##0) : "v"(db_ + 16ull*g));      \
    asm volatile("global_load_dwordx4 %0, %1, off" : "=v"(T##P##1) : "v"(db_ + 64 + 16ull*g)); \
    asm volatile("global_load_dword %0, %1, off"                                     \
                 : "=v"(win##P) : "v"((unsigned long long)(winner + dst##P)));       \
} while (0)

// Wait for all prefetch loads; leave the (exactly 3) compute stores in flight.
// "+v" operands create data deps so consumers can't hoist; "memory" keeps the
// stores above; sched_barrier stops any residual reordering (rule #18).
#define WAITPF(Q, P) do {                                                            \
    asm volatile("s_waitcnt vmcnt(3)"                                                \
        : "+v"(S##Q##a), "+v"(S##Q##b), "+v"(D##Q##a), "+v"(D##Q##b),                \
          "+v"(T##Q##0), "+v"(T##Q##1), "+v"(win##Q),                                \
          "+v"(sid##P), "+v"(dst##P), "+v"(ef##P), "+v"(dt##P) :: "memory");         \
    __builtin_amdgcn_sched_barrier(0);                                               \
} while (0)

    int gA = ewid, gB = ewid + EDGE_WAVES;
    if (gA < ngrp) {
        int eA, sidA, dstA, winA; f32x2v efA; float dtA;
        f32x4v SAa, SAb, DAa, DAb, TA0, TA1;
        int eB, sidB, dstB, winB; f32x2v efB; float dtB;
        f32x4v SBa, SBb, DBa, DBb, TB0, TB1;

        {   // prologue: group gA fully + ids for gB (plain loads; compiler waits)
            int ee = gA * 16 + eI; if (ee >= E) ee = E - 1;
            eA = ee;
            sidA = src_ids[ee]; dstA = dst_ids[ee];
            efA = ((const f32x2v*)edge_feat)[ee]; dtA = delta_t[ee];
            winA = winner[dstA];
            const f32x4v* sp_ = (const f32x4v*)memory + (size_t)sidA * 8;
            const f32x4v* dp_ = (const f32x4v*)memory + (size_t)dstA * 8;
            SAa = sp_[2*g]; SAb = sp_[2*g+1];
            DAa = dp_[2*g]; DAb = dp_[2*g+1];
            TA0 = dp_[g];   TA1 = dp_[4+g];
            int gp = (gB < ngrp) ? gB : (ngrp - 1);
            int ee2 = gp * 16 + eI; if (ee2 >= E) ee2 = E - 1;
            eB = ee2;
            sidB = src_ids[ee2]; dstB = dst_ids[ee2];
            efB = ((const f32x2v*)edge_feat)[ee2]; dtB = delta_t[ee2];
        }

        for (;;) {
            // ---- compute A; prefetch rows(B) + ids(A+2S) underneath ----
            ROWS_ASM(B);
            int gnA = gA + 2 * EDGE_WAVES;
            {
                int ce = eA, cd = dstA; f32x2v cef = efA; float cdt = dtA;
                int gp = (gnA < ngrp) ? gnA : (ngrp - 1);
                IDS_ASM(A, gp);
                compute16(gA, E, eI, g, lane, ce, cd, winA, cef, cdt,
                          SAa, SAb, DAa, DAb, TA0, TA1,
                          tb, frg, clsb2, probs, out_mem, trash);
            }
            if (gB >= ngrp) break;
            WAITPF(B, A);

            // ---- compute B; prefetch rows(A') + ids(B+2S) underneath ----
            ROWS_ASM(A);
            int gnB = gB + 2 * EDGE_WAVES;
            {
                int ce = eB, cd = dstB; f32x2v cef = efB; float cdt = dtB;
                int gp = (gnB < ngrp) ? gnB : (ngrp - 1);
                IDS_ASM(B, gp);
                compute16(gB, E, eI, g, lane, ce, cd, winB, cef, cdt,
                          SBa, SBb, DBa, DBb, TB0, TB1,
                          tb, frg, clsb2, probs, out_mem, trash);
            }
            gA = gnA;
            if (gA >= ngrp) break;
            WAITPF(A, B);
            gB = gnB;
        }
    }
#undef IDS_ASM
#undef ROWS_ASM
#undef WAITPF
}

extern "C" void kernel_launch(void* const* d_in, const int* in_sizes, int n_in,
                              void* d_out, int out_size, void* d_ws, size_t ws_size,
                              hipStream_t stream) {
    const int*   src_ids   = (const int*)d_in[0];
    const int*   dst_ids   = (const int*)d_in[1];
    const float* edge_feat = (const float*)d_in[2];
    const float* delta_t   = (const float*)d_in[3];
    const float* memory    = (const float*)d_in[4];
    const float* msg_W1 = (const float*)d_in[5],  *msg_b1 = (const float*)d_in[6];
    const float* msg_W2 = (const float*)d_in[7],  *msg_b2 = (const float*)d_in[8];
    const float* w_ih   = (const float*)d_in[9],  *b_ih   = (const float*)d_in[10];
    const float* w_hh   = (const float*)d_in[11], *b_hh   = (const float*)d_in[12];
    const float* Wv     = (const float*)d_in[13], *bv     = (const float*)d_in[14];
    const float* Wo     = (const float*)d_in[15], *bo     = (const float*)d_in[16];
    const float* emb_W1 = (const float*)d_in[17], *emb_b1 = (const float*)d_in[18];
    const float* emb_W2 = (const float*)d_in[19], *emb_b2 = (const float*)d_in[20];
    const float* cls_W1 = (const float*)d_in[21], *cls_b1 = (const float*)d_in[22];
    const float* cls_W2 = (const float*)d_in[23], *cls_b2 = (const float*)d_in[24];

    int E = in_sizes[0];
    int N = in_sizes[4] / 32;
    int ngrp = (E + 15) / 16;

    int*   winner = (int*)d_ws;
    float* WSf    = (float*)((char*)d_ws + (size_t)N * sizeof(int));
    float* probs  = (float*)d_out;
    float* outmem = probs + E;
    float* trash  = WSf + WC_OFF;   // WC region is dead after prep_k; 32 slots x 128B

    hipMemsetAsync(winner, 0, (size_t)N * sizeof(int), stream);
    winner_k<<<(E + 255) / 256, 256, 0, stream>>>(dst_ids, winner, E);
    prep_k<<<1, 256, 0, stream>>>(msg_W1, msg_b1, msg_W2, msg_b2,
                                  w_ih, b_ih, w_hh, b_hh,
                                  Wv, bv, Wo, bo,
                                  emb_W1, emb_b1, emb_W2, emb_b2,
                                  cls_W1, cls_b1, cls_W2, WSf);
    tgn_mfma16<<<GRID, BLK, 0, stream>>>(src_ids, dst_ids, edge_feat, delta_t,
                                         memory, cls_b2, WSf, winner,
                                         probs, outmem, trash, E, N, ngrp);
}

// Round 14
// 279.440 us; speedup vs baseline: 1.3769x; 1.0469x over previous
//
#include <hip/hip_runtime.h>
#include <hip/hip_bf16.h>

typedef float  f32x4v __attribute__((ext_vector_type(4)));
typedef short  bf16x8 __attribute__((ext_vector_type(8)));

#define NFRAG   26
#define TB_F32  512                            // 16 tables x 32 f32
#define FRG_U16 (NFRAG*512)                    // 26 frags x 64 lanes x 8 bf16
#define SHARE_BYTES (TB_F32*4 + FRG_U16*2)     // 28672 B staged to LDS
#define SHARE_U4 (SHARE_BYTES/16)              // 1792 uint4
#define WC_OFF 7168                            // WC scratch offset in WS floats

#define BLK 256
#define COPY_BLOCKS 256
#define EDGE_BLOCKS 768
#define GRID (COPY_BLOCKS + EDGE_BLOCKS)       // 1024 = 4 blocks/CU resident
#define EDGE_WAVES (EDGE_BLOCKS * 4)           // 3072

#define MFMA(a,b,c) __builtin_amdgcn_mfma_f32_16x16x32_bf16(a,b,c,0,0,0)

__device__ __forceinline__ float sigf(float v) {
    return __builtin_amdgcn_rcpf(1.0f + __expf(-v));
}
__device__ __forceinline__ float tanhf_fast(float v) {
    float a = fabsf(v);
    float t = __expf(-2.0f * a);
    float r = (1.0f - t) * __builtin_amdgcn_rcpf(1.0f + t);
    return v < 0.0f ? -r : r;
}
__device__ __forceinline__ unsigned pk(float a, float b) {   // bf16(a) lo | bf16(b) hi
    union { __hip_bfloat162 h; unsigned u; } c;
    c.h = __float22bfloat162_rn(make_float2(a, b));
    return c.u;
}

union FragU { uint4 u4; bf16x8 s8; unsigned u[4]; };

__device__ __forceinline__ bf16x8 ldfrag(const unsigned short* frg, int idx_u16) {
    FragU c; c.u4 = *(const uint4*)(frg + idx_u16); return c.s8;
}
__device__ __forceinline__ f32x4v tbl(const float* tb, int idx_f32) {
    return *(const f32x4v*)(tb + idx_f32);
}
// In-register D->B relayout (R9-verified): consumer A-frags are k-permuted so
// the lane's 8 D values ARE its B fragment. Zero cross-lane, zero LDS.
__device__ __forceinline__ bf16x8 relayout_reg(f32x4v h0, f32x4v h1) {
    FragU c;
    c.u[0] = pk(h0[0], h0[1]); c.u[1] = pk(h0[2], h0[3]);
    c.u[2] = pk(h1[0], h1[1]); c.u[3] = pk(h1[2], h1[3]);
    return c.s8;
}

__global__ void winner_k(const int* __restrict__ dst_ids, int* __restrict__ winner, int E) {
    int e = blockIdx.x * 256 + threadIdx.x;
    if (e < E) atomicMax(winner + dst_ids[e], e + 1);
}

// Small single-block prep: bias/tail tables + folded attn matrix WC.
__global__ void prep_wc_k(const float* __restrict__ msg_W1, const float* __restrict__ msg_b1,
                          const float* __restrict__ msg_b2,
                          const float* __restrict__ b_ih, const float* __restrict__ b_hh,
                          const float* __restrict__ Wv, const float* __restrict__ bv,
                          const float* __restrict__ Wo, const float* __restrict__ bo,
                          const float* __restrict__ emb_W1, const float* __restrict__ emb_b1,
                          const float* __restrict__ emb_b2,
                          const float* __restrict__ cls_b1, const float* __restrict__ cls_W2,
                          float* __restrict__ WSf) {
    int t = threadIdx.x;  // 256 threads
    float* tb = WSf;
    float* WC = WSf + WC_OFF;
    if (t < 32) {
        int j = t;
        tb[0*32+j]  = msg_b1[j];
        tb[1*32+j]  = msg_W1[j*67+64];
        tb[2*32+j]  = msg_W1[j*67+65];
        tb[3*32+j]  = msg_W1[j*67+66];
        tb[4*32+j]  = msg_b2[j];
        tb[5*32+j]  = b_ih[32+j] + b_hh[32+j];     // z bias
        tb[6*32+j]  = b_ih[j] + b_hh[j];           // r bias
        tb[7*32+j]  = b_hh[64+j];                  // h_n bias
        tb[8*32+j]  = b_ih[64+j];                  // i_n bias
        float a = bo[j];
        for (int o = 0; o < 32; ++o) a += Wo[j*32+o] * bv[o];
        tb[9*32+j]  = a;                           // folded attn bias
        tb[10*32+j] = emb_b1[j];
        tb[11*32+j] = emb_W1[j*34+32];
        tb[12*32+j] = emb_W1[j*34+33];
        tb[13*32+j] = emb_b2[j];
        tb[14*32+j] = cls_b1[j];
        tb[15*32+j] = cls_W2[j];
    }
    for (int i = t; i < 1024; i += 256) {
        int j = i >> 5, k = i & 31;
        float a = 0.0f;
        for (int o = 0; o < 32; ++o) a += Wo[j*32+o] * Wv[o*32+k];
        WC[i] = a;
    }
}

// One block per fragment (26 blocks x 256 threads).
__global__ void prep_frag_k(const float* __restrict__ msg_W1,
                            const float* __restrict__ msg_W2,
                            const float* __restrict__ w_ih,
                            const float* __restrict__ w_hh,
                            const float* __restrict__ emb_W1,
                            const float* __restrict__ emb_W2,
                            const float* __restrict__ cls_W1,
                            float* __restrict__ WSf) {
    int f = blockIdx.x;
    unsigned short* frg = (unsigned short*)(WSf + TB_F32);
    const float* WC = WSf + WC_OFF;
    for (int k2 = threadIdx.x; k2 < 512; k2 += 256) {
        int l = k2 >> 3, i = k2 & 7;
        int r = l & 15, kb = ((l >> 4) << 3) + i;
        const float* P; int j0 = 0, k0 = 0, ld = 32;
        bool mapped = false;
        switch (f) {
            case 0:  P = msg_W1; j0 = 0;  k0 = 0;  ld = 67; break;
            case 1:  P = msg_W1; j0 = 0;  k0 = 32; ld = 67; break;
            case 2:  P = msg_W1; j0 = 16; k0 = 0;  ld = 67; break;
            case 3:  P = msg_W1; j0 = 16; k0 = 32; ld = 67; break;
            case 4:  P = msg_W2; j0 = 0;  mapped = true; break;
            case 5:  P = msg_W2; j0 = 16; mapped = true; break;
            case 6:  P = w_ih;   j0 = 32; mapped = true; break;   // z ih
            case 7:  P = w_hh;   j0 = 32; break;                  // z hh
            case 8:  P = w_ih;   j0 = 48; mapped = true; break;
            case 9:  P = w_hh;   j0 = 48; break;
            case 10: P = w_ih;   j0 = 0;  mapped = true; break;   // r ih
            case 11: P = w_hh;   j0 = 0;  break;
            case 12: P = w_ih;   j0 = 16; mapped = true; break;
            case 13: P = w_hh;   j0 = 16; break;
            case 14: P = w_hh;   j0 = 64; break;                  // n hh
            case 15: P = w_hh;   j0 = 80; break;
            case 16: P = w_ih;   j0 = 64; mapped = true; break;   // n ih
            case 17: P = w_ih;   j0 = 80; mapped = true; break;
            case 18: P = WC;     j0 = 0;  break;                  // folded attn
            case 19: P = WC;     j0 = 16; break;
            case 20: P = emb_W1; j0 = 0;  ld = 34; mapped = true; break;
            case 21: P = emb_W1; j0 = 16; ld = 34; mapped = true; break;
            case 22: P = emb_W2; j0 = 0;  mapped = true; break;
            case 23: P = emb_W2; j0 = 16; mapped = true; break;
            case 24: P = cls_W1; j0 = 0;  mapped = true; break;
            default: P = cls_W1; j0 = 16; mapped = true; break;
        }
        int kidx = kb;
        if (mapped) kidx = 16 * ((kb >> 2) & 1) + 4 * (kb >> 3) + (kb & 3);
        __hip_bfloat16 hv = __float2bfloat16(P[(j0 + r) * ld + k0 + kidx]);
        frg[f * 512 + k2] = *(unsigned short*)&hv;
    }
}

// Two independent dependency chains interleaved at source:
//   chain A: msg1 -> msg2 -> GRU(z,r,hn,n) -> blend -> winner store
//   chain B: attn -> emb1 -> emb2 -> cls  -> probs
__device__ __forceinline__ void compute16(
    int grp, int E, int eI, int g, int lane,
    int e, int dst, int winv, float2 ef, float dtv,
    f32x4v sa, f32x4v sb, f32x4v da, f32x4v db, f32x4v t0, f32x4v t1,
    const float* tb, const unsigned short* frg, float clsb2,
    float* __restrict__ probs, float* __restrict__ out_mem) {
    int ob = 0, tbo = 0;
    asm volatile("" : "+v"(ob), "+v"(tbo));  // block LICM of LDS frag/table reads

#define LFX(f) ldfrag(frg, (f) * 512 + lane * 8 + ob)
#define TBX(t_, jt_) tbl(tb, (t_) * 32 + (jt_) * 16 + 4 * g + tbo)

    FragU Bs, Bd;
    Bs.u[0] = pk(sa[0], sa[1]); Bs.u[1] = pk(sa[2], sa[3]);
    Bs.u[2] = pk(sb[0], sb[1]); Bs.u[3] = pk(sb[2], sb[3]);
    Bd.u[0] = pk(da[0], da[1]); Bd.u[1] = pk(da[2], da[3]);
    Bd.u[2] = pk(db[0], db[1]); Bd.u[3] = pk(db[2], db[3]);
    f32x4v dmt0 = t0, dmt1 = t1;

    // [A1] msg1: relu(W1 @ [sm, dm, ef, dt] + b1)
    f32x4v h0, h1;
    {
        f32x4v b0 = TBX(0,0), wa0 = TBX(1,0), wb0 = TBX(2,0), wc0 = TBX(3,0);
        f32x4v b1 = TBX(0,1), wa1 = TBX(1,1), wb1 = TBX(2,1), wc1 = TBX(3,1);
        f32x4v c0, c1;
#pragma unroll
        for (int i = 0; i < 4; ++i) {
            c0[i] = b0[i] + ef.x * wa0[i] + ef.y * wb0[i] + dtv * wc0[i];
            c1[i] = b1[i] + ef.x * wa1[i] + ef.y * wb1[i] + dtv * wc1[i];
        }
        c0 = MFMA(LFX(1), Bd.s8, c0); c0 = MFMA(LFX(0), Bs.s8, c0);
        c1 = MFMA(LFX(3), Bd.s8, c1); c1 = MFMA(LFX(2), Bs.s8, c1);
        h0 = c0; h1 = c1;
    }
    // [B1] attn (independent of A-chain: needs only Bd)
    f32x4v at0 = MFMA(LFX(18), Bd.s8, TBX(9,0));
    f32x4v at1 = MFMA(LFX(19), Bd.s8, TBX(9,1));
    // [A1 post] relu -> Bh
#pragma unroll
    for (int i = 0; i < 4; ++i) { h0[i] = fmaxf(h0[i], 0.0f); h1[i] = fmaxf(h1[i], 0.0f); }
    bf16x8 Bh = relayout_reg(h0, h1);
    // [A2] msg2
    f32x4v m0 = MFMA(LFX(4), Bh, TBX(4,0));
    f32x4v m1 = MFMA(LFX(5), Bh, TBX(4,1));
    // [B1 post] Ba ; [B2] emb1
    bf16x8 Ba = relayout_reg(at0, at1);
    f32x4v e10, e11;
    {
        f32x4v b0 = TBX(10,0), wa0 = TBX(11,0), wb0 = TBX(12,0);
        f32x4v b1 = TBX(10,1), wa1 = TBX(11,1), wb1 = TBX(12,1);
        f32x4v c0, c1;
#pragma unroll
        for (int i = 0; i < 4; ++i) {
            c0[i] = b0[i] + ef.x * wa0[i] + ef.y * wb0[i];
            c1[i] = b1[i] + ef.x * wa1[i] + ef.y * wb1[i];
        }
        e10 = MFMA(LFX(20), Ba, c0);
        e11 = MFMA(LFX(21), Ba, c1);
    }
    // [A2 post] Bm ; [A3] GRU z
    bf16x8 Bm = relayout_reg(m0, m1);
    f32x4v z0 = TBX(5,0); z0 = MFMA(LFX(7), Bd.s8, z0); z0 = MFMA(LFX(6), Bm, z0);
    f32x4v z1 = TBX(5,1); z1 = MFMA(LFX(9), Bd.s8, z1); z1 = MFMA(LFX(8), Bm, z1);
    // [B2 post] relu -> B1 ; [B3] emb2
#pragma unroll
    for (int i = 0; i < 4; ++i) { e10[i] = fmaxf(e10[i], 0.0f); e11[i] = fmaxf(e11[i], 0.0f); }
    bf16x8 B1 = relayout_reg(e10, e11);
    f32x4v e20 = MFMA(LFX(22), B1, TBX(13,0));
    f32x4v e21 = MFMA(LFX(23), B1, TBX(13,1));
    // [A3 post] sigmoid z ; [A4] r + hn
#pragma unroll
    for (int i = 0; i < 4; ++i) { z0[i] = sigf(z0[i]); z1[i] = sigf(z1[i]); }
    f32x4v r0 = TBX(6,0); r0 = MFMA(LFX(11), Bd.s8, r0); r0 = MFMA(LFX(10), Bm, r0);
    f32x4v r1 = TBX(6,1); r1 = MFMA(LFX(13), Bd.s8, r1); r1 = MFMA(LFX(12), Bm, r1);
    f32x4v hn0 = TBX(7,0); hn0 = MFMA(LFX(14), Bd.s8, hn0);
    f32x4v hn1 = TBX(7,1); hn1 = MFMA(LFX(15), Bd.s8, hn1);
    // [B3 post] B2 ; [B4] cls
    bf16x8 B2 = relayout_reg(e20, e21);
    f32x4v cc0 = MFMA(LFX(24), B2, TBX(14,0));
    f32x4v cc1 = MFMA(LFX(25), B2, TBX(14,1));
    // [A4 post] n pre-act + n MFMA
    f32x4v bin0 = TBX(8,0), bin1 = TBX(8,1);
    f32x4v np0, np1;
#pragma unroll
    for (int i = 0; i < 4; ++i) {
        np0[i] = fmaf(sigf(r0[i]), hn0[i], bin0[i]);
        np1[i] = fmaf(sigf(r1[i]), hn1[i], bin1[i]);
    }
    np0 = MFMA(LFX(16), Bm, np0);
    np1 = MFMA(LFX(17), Bm, np1);
    // [B4 post] cls dot
    float part = 0.0f;
    {
        f32x4v w20 = TBX(15,0), w21 = TBX(15,1);
#pragma unroll
        for (int i = 0; i < 4; ++i) {
            part = fmaf(fmaxf(cc0[i], 0.0f), w20[i], part);
            part = fmaf(fmaxf(cc1[i], 0.0f), w21[i], part);
        }
    }
    // [A5] blend + winner store
    f32x4v u0, u1;
#pragma unroll
    for (int i = 0; i < 4; ++i) {
        float n0 = tanhf_fast(np0[i]);
        float n1 = tanhf_fast(np1[i]);
        u0[i] = n0 + z0[i] * (dmt0[i] - n0);
        u1[i] = n1 + z1[i] * (dmt1[i] - n1);
    }
    if (winv == e + 1) {
        f32x4v* orow = (f32x4v*)(out_mem + (size_t)dst * 32);
        orow[g]     = u0;
        orow[4 + g] = u1;
    }
    // probs
    part += __shfl_xor(part, 16);
    part += __shfl_xor(part, 32);
    if (lane < 16) {
        int ee = grp * 16 + eI;
        if (ee < E) probs[ee] = sigf(part + clsb2);
    }
#undef LFX
#undef TBX
}

__global__ __launch_bounds__(BLK, 4) void tgn_mfma16(
    const int* __restrict__ src_ids, const int* __restrict__ dst_ids,
    const float* __restrict__ edge_feat, const float* __restrict__ delta_t,
    const float* __restrict__ memory, const float* __restrict__ cls_b2,
    const float* __restrict__ WSf, const int* __restrict__ winner,
    float* __restrict__ probs, float* __restrict__ out_mem,
    int E, int N, int ngrp) {
    __shared__ uint4 sbuf[SHARE_U4];
    int bid = blockIdx.x, tid = threadIdx.x;

    if (bid < COPY_BLOCKS) {  // copy workers: non-winner rows -> out_mem
        const f32x4v* m4 = (const f32x4v*)memory;
        f32x4v* o4 = (f32x4v*)out_mem;
        const long S = (long)COPY_BLOCKS * BLK;
        const long total4 = (long)N * 8;
        long i0 = (long)bid * BLK + tid;
        for (; i0 + 3 * S < total4; i0 += 4 * S) {
            long i1 = i0 + S, i2 = i0 + 2 * S, i3 = i0 + 3 * S;
            int w0 = winner[i0 >> 3];
            int w1 = winner[i1 >> 3];
            int w2 = winner[i2 >> 3];
            int w3 = winner[i3 >> 3];
            if (w0 == 0) o4[i0] = m4[i0];
            if (w1 == 0) o4[i1] = m4[i1];
            if (w2 == 0) o4[i2] = m4[i2];
            if (w3 == 0) o4[i3] = m4[i3];
        }
        for (; i0 < total4; i0 += S) {
            if (winner[i0 >> 3] == 0) o4[i0] = m4[i0];
        }
        return;
    }

    {   // stage tables + A-fragments into LDS
        const uint4* s = (const uint4*)WSf;
        for (int i = tid; i < SHARE_U4; i += BLK) sbuf[i] = s[i];
    }
    __syncthreads();
    const float* tb = (const float*)sbuf;
    const unsigned short* frg = (const unsigned short*)((const float*)sbuf + TB_F32);
    int wv = tid >> 6, lane = tid & 63;
    int eI = lane & 15, g = lane >> 4;
    int ewid = (bid - COPY_BLOCKS) * 4 + wv;
    float clsb2 = cls_b2[0];

#define PREF(P, G) do {                                                              \
    int ee = (G) * 16 + eI; if (ee >= E) ee = E - 1;                                 \
    e##P = ee;                                                                       \
    int sid = src_ids[ee]; dst##P = dst_ids[ee];                                     \
    ef##P = ((const float2*)edge_feat)[ee]; dt##P = delta_t[ee];                     \
    win##P = winner[dst##P];                                                         \
    const f32x4v* sp_ = (const f32x4v*)(memory + (size_t)sid * 32);                  \
    const f32x4v* dp_ = (const f32x4v*)(memory + (size_t)dst##P * 32);               \
    S##P##a = sp_[2*g]; S##P##b = sp_[2*g+1];                                        \
    D##P##a = dp_[2*g]; D##P##b = dp_[2*g+1];                                        \
    T##P##0 = dp_[g];   T##P##1 = dp_[4+g];                                          \
} while (0)

    int g0 = ewid;
    if (g0 < ngrp) {
        int eA, dstA, winA; float2 efA; float dtA;
        f32x4v SAa, SAb, DAa, DAb, TA0, TA1;
        int eB, dstB, winB; float2 efB; float dtB;
        f32x4v SBa, SBb, DBa, DBb, TB0, TB1;
        PREF(A, g0);
        for (;;) {
            int gn = g0 + EDGE_WAVES;
            { int gp = (gn < ngrp) ? gn : (ngrp - 1); PREF(B, gp); }
            asm volatile("" ::: "memory");
            compute16(g0, E, eI, g, lane, eA, dstA, winA, efA, dtA,
                      SAa, SAb, DAa, DAb, TA0, TA1,
                      tb, frg, clsb2, probs, out_mem);
            if (gn >= ngrp) break;
            g0 = gn;
            gn = g0 + EDGE_WAVES;
            { int gp = (gn < ngrp) ? gn : (ngrp - 1); PREF(A, gp); }
            asm volatile("" ::: "memory");
            compute16(g0, E, eI, g, lane, eB, dstB, winB, efB, dtB,
                      SBa, SBb, DBa, DBb, TB0, TB1,
                      tb, frg, clsb2, probs, out_mem);
            if (gn >= ngrp) break;
            g0 = gn;
        }
    }
#undef PREF
}

extern "C" void kernel_launch(void* const* d_in, const int* in_sizes, int n_in,
                              void* d_out, int out_size, void* d_ws, size_t ws_size,
                              hipStream_t stream) {
    const int*   src_ids   = (const int*)d_in[0];
    const int*   dst_ids   = (const int*)d_in[1];
    const float* edge_feat = (const float*)d_in[2];
    const float* delta_t   = (const float*)d_in[3];
    const float* memory    = (const float*)d_in[4];
    const float* msg_W1 = (const float*)d_in[5],  *msg_b1 = (const float*)d_in[6];
    const float* msg_W2 = (const float*)d_in[7],  *msg_b2 = (const float*)d_in[8];
    const float* w_ih   = (const float*)d_in[9],  *b_ih   = (const float*)d_in[10];
    const float* w_hh   = (const float*)d_in[11], *b_hh   = (const float*)d_in[12];
    const float* Wv     = (const float*)d_in[13], *bv     = (const float*)d_in[14];
    const float* Wo     = (const float*)d_in[15], *bo     = (const float*)d_in[16];
    const float* emb_W1 = (const float*)d_in[17], *emb_b1 = (const float*)d_in[18];
    const float* emb_W2 = (const float*)d_in[19], *emb_b2 = (const float*)d_in[20];
    const float* cls_W1 = (const float*)d_in[21], *cls_b1 = (const float*)d_in[22];
    const float* cls_W2 = (const float*)d_in[23], *cls_b2 = (const float*)d_in[24];

    int E = in_sizes[0];
    int N = in_sizes[4] / 32;
    int ngrp = (E + 15) / 16;

    int*   winner = (int*)d_ws;
    float* WSf    = (float*)((char*)d_ws + (size_t)N * sizeof(int));
    float* probs  = (float*)d_out;
    float* outmem = probs + E;

    hipMemsetAsync(winner, 0, (size_t)N * sizeof(int), stream);
    winner_k<<<(E + 255) / 256, 256, 0, stream>>>(dst_ids, winner, E);
    prep_wc_k<<<1, 256, 0, stream>>>(msg_W1, msg_b1, msg_b2, b_ih, b_hh,
                                     Wv, bv, Wo, bo, emb_W1, emb_b1, emb_b2,
                                     cls_b1, cls_W2, WSf);
    prep_frag_k<<<NFRAG, 256, 0, stream>>>(msg_W1, msg_W2, w_ih, w_hh,
                                           emb_W1, emb_W2, cls_W1, WSf);
    tgn_mfma16<<<GRID, BLK, 0, stream>>>(src_ids, dst_ids, edge_feat, delta_t,
                                         memory, cls_b2, WSf, winner,
                                         probs, outmem, E, N, ngrp);
}

// Round 15
// 270.568 us; speedup vs baseline: 1.4221x; 1.0328x over previous
//
#include <hip/hip_runtime.h>
#include <hip/hip_bf16.h>

typedef float  f32x4v __attribute__((ext_vector_type(4)));
typedef short  bf16x8 __attribute__((ext_vector_type(8)));

#define NFRAG   26
#define TB_F32  512                            // 16 tables x 32 f32
#define FRG_U16 (NFRAG*512)                    // 26 frags x 64 lanes x 8 bf16
#define SHARE_BYTES (TB_F32*4 + FRG_U16*2)     // 28672 B staged to LDS
#define SHARE_U4 (SHARE_BYTES/16)              // 1792 uint4
#define WC_OFF 7168                            // WC scratch offset in WS floats

#define BLK 512                                // 8 waves share one LDS image
#define COPY_BLOCKS 192
#define EDGE_BLOCKS 576
#define GRID (COPY_BLOCKS + EDGE_BLOCKS)       // 768 = 3 blocks/CU = 24 waves/CU
#define EDGE_WAVES (EDGE_BLOCKS * 8)           // 4608

#define MFMA(a,b,c) __builtin_amdgcn_mfma_f32_16x16x32_bf16(a,b,c,0,0,0)

__device__ __forceinline__ float sigf(float v) {
    return __builtin_amdgcn_rcpf(1.0f + __expf(-v));
}
__device__ __forceinline__ float tanhf_fast(float v) {
    float a = fabsf(v);
    float t = __expf(-2.0f * a);
    float r = (1.0f - t) * __builtin_amdgcn_rcpf(1.0f + t);
    return v < 0.0f ? -r : r;
}
__device__ __forceinline__ unsigned pk(float a, float b) {   // bf16(a) lo | bf16(b) hi
    union { __hip_bfloat162 h; unsigned u; } c;
    c.h = __float22bfloat162_rn(make_float2(a, b));
    return c.u;
}

union FragU { uint4 u4; bf16x8 s8; unsigned u[4]; };

__device__ __forceinline__ bf16x8 ldfrag(const unsigned short* frg, int idx_u16) {
    FragU c; c.u4 = *(const uint4*)(frg + idx_u16); return c.s8;
}
__device__ __forceinline__ f32x4v tbl(const float* tb, int idx_f32) {
    return *(const f32x4v*)(tb + idx_f32);
}
// In-register D->B relayout (R9-verified): consumer A-frags are k-permuted so
// the lane's 8 D values ARE its B fragment. Zero cross-lane, zero LDS.
__device__ __forceinline__ bf16x8 relayout_reg(f32x4v h0, f32x4v h1) {
    FragU c;
    c.u[0] = pk(h0[0], h0[1]); c.u[1] = pk(h0[2], h0[3]);
    c.u[2] = pk(h1[0], h1[1]); c.u[3] = pk(h1[2], h1[3]);
    return c.s8;
}

__global__ void winner_k(const int* __restrict__ dst_ids, int* __restrict__ winner, int E) {
    int e = blockIdx.x * 256 + threadIdx.x;
    if (e < E) atomicMax(winner + dst_ids[e], e + 1);
}

// Small single-block prep: bias/tail tables + folded attn matrix WC.
__global__ void prep_wc_k(const float* __restrict__ msg_W1, const float* __restrict__ msg_b1,
                          const float* __restrict__ msg_b2,
                          const float* __restrict__ b_ih, const float* __restrict__ b_hh,
                          const float* __restrict__ Wv, const float* __restrict__ bv,
                          const float* __restrict__ Wo, const float* __restrict__ bo,
                          const float* __restrict__ emb_W1, const float* __restrict__ emb_b1,
                          const float* __restrict__ emb_b2,
                          const float* __restrict__ cls_b1, const float* __restrict__ cls_W2,
                          float* __restrict__ WSf) {
    int t = threadIdx.x;  // 256 threads
    float* tb = WSf;
    float* WC = WSf + WC_OFF;
    if (t < 32) {
        int j = t;
        tb[0*32+j]  = msg_b1[j];
        tb[1*32+j]  = msg_W1[j*67+64];
        tb[2*32+j]  = msg_W1[j*67+65];
        tb[3*32+j]  = msg_W1[j*67+66];
        tb[4*32+j]  = msg_b2[j];
        tb[5*32+j]  = b_ih[32+j] + b_hh[32+j];     // z bias
        tb[6*32+j]  = b_ih[j] + b_hh[j];           // r bias
        tb[7*32+j]  = b_hh[64+j];                  // h_n bias
        tb[8*32+j]  = b_ih[64+j];                  // i_n bias
        float a = bo[j];
        for (int o = 0; o < 32; ++o) a += Wo[j*32+o] * bv[o];
        tb[9*32+j]  = a;                           // folded attn bias
        tb[10*32+j] = emb_b1[j];
        tb[11*32+j] = emb_W1[j*34+32];
        tb[12*32+j] = emb_W1[j*34+33];
        tb[13*32+j] = emb_b2[j];
        tb[14*32+j] = cls_b1[j];
        tb[15*32+j] = cls_W2[j];
    }
    for (int i = t; i < 1024; i += 256) {
        int j = i >> 5, k = i & 31;
        float a = 0.0f;
        for (int o = 0; o < 32; ++o) a += Wo[j*32+o] * Wv[o*32+k];
        WC[i] = a;
    }
}

// One block per fragment (26 blocks x 256 threads).
__global__ void prep_frag_k(const float* __restrict__ msg_W1,
                            const float* __restrict__ msg_W2,
                            const float* __restrict__ w_ih,
                            const float* __restrict__ w_hh,
                            const float* __restrict__ emb_W1,
                            const float* __restrict__ emb_W2,
                            const float* __restrict__ cls_W1,
                            float* __restrict__ WSf) {
    int f = blockIdx.x;
    unsigned short* frg = (unsigned short*)(WSf + TB_F32);
    const float* WC = WSf + WC_OFF;
    for (int k2 = threadIdx.x; k2 < 512; k2 += 256) {
        int l = k2 >> 3, i = k2 & 7;
        int r = l & 15, kb = ((l >> 4) << 3) + i;
        const float* P; int j0 = 0, k0 = 0, ld = 32;
        bool mapped = false;
        switch (f) {
            case 0:  P = msg_W1; j0 = 0;  k0 = 0;  ld = 67; break;
            case 1:  P = msg_W1; j0 = 0;  k0 = 32; ld = 67; break;
            case 2:  P = msg_W1; j0 = 16; k0 = 0;  ld = 67; break;
            case 3:  P = msg_W1; j0 = 16; k0 = 32; ld = 67; break;
            case 4:  P = msg_W2; j0 = 0;  mapped = true; break;
            case 5:  P = msg_W2; j0 = 16; mapped = true; break;
            case 6:  P = w_ih;   j0 = 32; mapped = true; break;   // z ih
            case 7:  P = w_hh;   j0 = 32; break;                  // z hh
            case 8:  P = w_ih;   j0 = 48; mapped = true; break;
            case 9:  P = w_hh;   j0 = 48; break;
            case 10: P = w_ih;   j0 = 0;  mapped = true; break;   // r ih
            case 11: P = w_hh;   j0 = 0;  break;
            case 12: P = w_ih;   j0 = 16; mapped = true; break;
            case 13: P = w_hh;   j0 = 16; break;
            case 14: P = w_hh;   j0 = 64; break;                  // n hh
            case 15: P = w_hh;   j0 = 80; break;
            case 16: P = w_ih;   j0 = 64; mapped = true; break;   // n ih
            case 17: P = w_ih;   j0 = 80; mapped = true; break;
            case 18: P = WC;     j0 = 0;  break;                  // folded attn
            case 19: P = WC;     j0 = 16; break;
            case 20: P = emb_W1; j0 = 0;  ld = 34; mapped = true; break;
            case 21: P = emb_W1; j0 = 16; ld = 34; mapped = true; break;
            case 22: P = emb_W2; j0 = 0;  mapped = true; break;
            case 23: P = emb_W2; j0 = 16; mapped = true; break;
            case 24: P = cls_W1; j0 = 0;  mapped = true; break;
            default: P = cls_W1; j0 = 16; mapped = true; break;
        }
        int kidx = kb;
        if (mapped) kidx = 16 * ((kb >> 2) & 1) + 4 * (kb >> 3) + (kb & 3);
        __hip_bfloat16 hv = __float2bfloat16(P[(j0 + r) * ld + k0 + kidx]);
        frg[f * 512 + k2] = *(unsigned short*)&hv;
    }
}

// Two independent dependency chains interleaved at source (R14-verified):
//   chain A: msg1 -> msg2 -> GRU(z,r,hn,n) -> blend -> winner store
//   chain B: attn -> emb1 -> emb2 -> cls  -> probs
__device__ __forceinline__ void compute16(
    int grp, int E, int eI, int g, int lane,
    int e, int dst, int winv, float2 ef, float dtv,
    f32x4v sa, f32x4v sb, f32x4v da, f32x4v db, f32x4v t0, f32x4v t1,
    const float* tb, const unsigned short* frg, float clsb2,
    float* __restrict__ probs, float* __restrict__ out_mem) {
    int ob = 0, tbo = 0;
    asm volatile("" : "+v"(ob), "+v"(tbo));  // block LICM of LDS frag/table reads

#define LFX(f) ldfrag(frg, (f) * 512 + lane * 8 + ob)
#define TBX(t_, jt_) tbl(tb, (t_) * 32 + (jt_) * 16 + 4 * g + tbo)

    FragU Bs, Bd;
    Bs.u[0] = pk(sa[0], sa[1]); Bs.u[1] = pk(sa[2], sa[3]);
    Bs.u[2] = pk(sb[0], sb[1]); Bs.u[3] = pk(sb[2], sb[3]);
    Bd.u[0] = pk(da[0], da[1]); Bd.u[1] = pk(da[2], da[3]);
    Bd.u[2] = pk(db[0], db[1]); Bd.u[3] = pk(db[2], db[3]);
    f32x4v dmt0 = t0, dmt1 = t1;

    // [A1] msg1: relu(W1 @ [sm, dm, ef, dt] + b1)
    f32x4v h0, h1;
    {
        f32x4v b0 = TBX(0,0), wa0 = TBX(1,0), wb0 = TBX(2,0), wc0 = TBX(3,0);
        f32x4v b1 = TBX(0,1), wa1 = TBX(1,1), wb1 = TBX(2,1), wc1 = TBX(3,1);
        f32x4v c0, c1;
#pragma unroll
        for (int i = 0; i < 4; ++i) {
            c0[i] = b0[i] + ef.x * wa0[i] + ef.y * wb0[i] + dtv * wc0[i];
            c1[i] = b1[i] + ef.x * wa1[i] + ef.y * wb1[i] + dtv * wc1[i];
        }
        c0 = MFMA(LFX(1), Bd.s8, c0); c0 = MFMA(LFX(0), Bs.s8, c0);
        c1 = MFMA(LFX(3), Bd.s8, c1); c1 = MFMA(LFX(2), Bs.s8, c1);
        h0 = c0; h1 = c1;
    }
    // [B1] attn (independent of A-chain: needs only Bd)
    f32x4v at0 = MFMA(LFX(18), Bd.s8, TBX(9,0));
    f32x4v at1 = MFMA(LFX(19), Bd.s8, TBX(9,1));
    // [A1 post] relu -> Bh
#pragma unroll
    for (int i = 0; i < 4; ++i) { h0[i] = fmaxf(h0[i], 0.0f); h1[i] = fmaxf(h1[i], 0.0f); }
    bf16x8 Bh = relayout_reg(h0, h1);
    // [A2] msg2
    f32x4v m0 = MFMA(LFX(4), Bh, TBX(4,0));
    f32x4v m1 = MFMA(LFX(5), Bh, TBX(4,1));
    // [B1 post] Ba ; [B2] emb1
    bf16x8 Ba = relayout_reg(at0, at1);
    f32x4v e10, e11;
    {
        f32x4v b0 = TBX(10,0), wa0 = TBX(11,0), wb0 = TBX(12,0);
        f32x4v b1 = TBX(10,1), wa1 = TBX(11,1), wb1 = TBX(12,1);
        f32x4v c0, c1;
#pragma unroll
        for (int i = 0; i < 4; ++i) {
            c0[i] = b0[i] + ef.x * wa0[i] + ef.y * wb0[i];
            c1[i] = b1[i] + ef.x * wa1[i] + ef.y * wb1[i];
        }
        e10 = MFMA(LFX(20), Ba, c0);
        e11 = MFMA(LFX(21), Ba, c1);
    }
    // [A2 post] Bm ; [A3] GRU z
    bf16x8 Bm = relayout_reg(m0, m1);
    f32x4v z0 = TBX(5,0); z0 = MFMA(LFX(7), Bd.s8, z0); z0 = MFMA(LFX(6), Bm, z0);
    f32x4v z1 = TBX(5,1); z1 = MFMA(LFX(9), Bd.s8, z1); z1 = MFMA(LFX(8), Bm, z1);
    // [B2 post] relu -> B1 ; [B3] emb2
#pragma unroll
    for (int i = 0; i < 4; ++i) { e10[i] = fmaxf(e10[i], 0.0f); e11[i] = fmaxf(e11[i], 0.0f); }
    bf16x8 B1 = relayout_reg(e10, e11);
    f32x4v e20 = MFMA(LFX(22), B1, TBX(13,0));
    f32x4v e21 = MFMA(LFX(23), B1, TBX(13,1));
    // [A3 post] sigmoid z ; [A4] r + hn
#pragma unroll
    for (int i = 0; i < 4; ++i) { z0[i] = sigf(z0[i]); z1[i] = sigf(z1[i]); }
    f32x4v r0 = TBX(6,0); r0 = MFMA(LFX(11), Bd.s8, r0); r0 = MFMA(LFX(10), Bm, r0);
    f32x4v r1 = TBX(6,1); r1 = MFMA(LFX(13), Bd.s8, r1); r1 = MFMA(LFX(12), Bm, r1);
    f32x4v hn0 = TBX(7,0); hn0 = MFMA(LFX(14), Bd.s8, hn0);
    f32x4v hn1 = TBX(7,1); hn1 = MFMA(LFX(15), Bd.s8, hn1);
    // [B3 post] B2 ; [B4] cls
    bf16x8 B2 = relayout_reg(e20, e21);
    f32x4v cc0 = MFMA(LFX(24), B2, TBX(14,0));
    f32x4v cc1 = MFMA(LFX(25), B2, TBX(14,1));
    // [A4 post] n pre-act + n MFMA
    f32x4v bin0 = TBX(8,0), bin1 = TBX(8,1);
    f32x4v np0, np1;
#pragma unroll
    for (int i = 0; i < 4; ++i) {
        np0[i] = fmaf(sigf(r0[i]), hn0[i], bin0[i]);
        np1[i] = fmaf(sigf(r1[i]), hn1[i], bin1[i]);
    }
    np0 = MFMA(LFX(16), Bm, np0);
    np1 = MFMA(LFX(17), Bm, np1);
    // [B4 post] cls dot
    float part = 0.0f;
    {
        f32x4v w20 = TBX(15,0), w21 = TBX(15,1);
#pragma unroll
        for (int i = 0; i < 4; ++i) {
            part = fmaf(fmaxf(cc0[i], 0.0f), w20[i], part);
            part = fmaf(fmaxf(cc1[i], 0.0f), w21[i], part);
        }
    }
    // [A5] blend + winner store
    f32x4v u0, u1;
#pragma unroll
    for (int i = 0; i < 4; ++i) {
        float n0 = tanhf_fast(np0[i]);
        float n1 = tanhf_fast(np1[i]);
        u0[i] = n0 + z0[i] * (dmt0[i] - n0);
        u1[i] = n1 + z1[i] * (dmt1[i] - n1);
    }
    if (winv == e + 1) {
        f32x4v* orow = (f32x4v*)(out_mem + (size_t)dst * 32);
        orow[g]     = u0;
        orow[4 + g] = u1;
    }
    // probs
    part += __shfl_xor(part, 16);
    part += __shfl_xor(part, 32);
    if (lane < 16) {
        int ee = grp * 16 + eI;
        if (ee < E) probs[ee] = sigf(part + clsb2);
    }
#undef LFX
#undef TBX
}

__global__ __launch_bounds__(BLK, 6) void tgn_mfma16(
    const int* __restrict__ src_ids, const int* __restrict__ dst_ids,
    const float* __restrict__ edge_feat, const float* __restrict__ delta_t,
    const float* __restrict__ memory, const float* __restrict__ cls_b2,
    const float* __restrict__ WSf, const int* __restrict__ winner,
    float* __restrict__ probs, float* __restrict__ out_mem,
    int E, int N, int ngrp) {
    __shared__ uint4 sbuf[SHARE_U4];
    int bid = blockIdx.x, tid = threadIdx.x;

    if (bid < COPY_BLOCKS) {  // copy workers: non-winner rows -> out_mem
        const f32x4v* m4 = (const f32x4v*)memory;
        f32x4v* o4 = (f32x4v*)out_mem;
        const long S = (long)COPY_BLOCKS * BLK;
        const long total4 = (long)N * 8;
        long i0 = (long)bid * BLK + tid;
        for (; i0 + 3 * S < total4; i0 += 4 * S) {
            long i1 = i0 + S, i2 = i0 + 2 * S, i3 = i0 + 3 * S;
            int w0 = winner[i0 >> 3];
            int w1 = winner[i1 >> 3];
            int w2 = winner[i2 >> 3];
            int w3 = winner[i3 >> 3];
            if (w0 == 0) o4[i0] = m4[i0];
            if (w1 == 0) o4[i1] = m4[i1];
            if (w2 == 0) o4[i2] = m4[i2];
            if (w3 == 0) o4[i3] = m4[i3];
        }
        for (; i0 < total4; i0 += S) {
            if (winner[i0 >> 3] == 0) o4[i0] = m4[i0];
        }
        return;
    }

    {   // stage tables + A-fragments into LDS (shared by 8 waves)
        const uint4* s = (const uint4*)WSf;
        for (int i = tid; i < SHARE_U4; i += BLK) sbuf[i] = s[i];
    }
    __syncthreads();
    const float* tb = (const float*)sbuf;
    const unsigned short* frg = (const unsigned short*)((const float*)sbuf + TB_F32);
    int wv = tid >> 6, lane = tid & 63;
    int eI = lane & 15, g = lane >> 4;
    int ewid = (bid - COPY_BLOCKS) * 8 + wv;
    float clsb2 = cls_b2[0];

#define PREF(P, G) do {                                                              \
    int ee = (G) * 16 + eI; if (ee >= E) ee = E - 1;                                 \
    e##P = ee;                                                                       \
    int sid = src_ids[ee]; dst##P = dst_ids[ee];                                     \
    ef##P = ((const float2*)edge_feat)[ee]; dt##P = delta_t[ee];                     \
    win##P = winner[dst##P];                                                         \
    const f32x4v* sp_ = (const f32x4v*)(memory + (size_t)sid * 32);                  \
    const f32x4v* dp_ = (const f32x4v*)(memory + (size_t)dst##P * 32);               \
    S##P##a = sp_[2*g]; S##P##b = sp_[2*g+1];                                        \
    D##P##a = dp_[2*g]; D##P##b = dp_[2*g+1];                                        \
    T##P##0 = dp_[g];   T##P##1 = dp_[4+g];                                          \
} while (0)

    int g0 = ewid;
    if (g0 < ngrp) {
        int eA, dstA, winA; float2 efA; float dtA;
        f32x4v SAa, SAb, DAa, DAb, TA0, TA1;
        int eB, dstB, winB; float2 efB; float dtB;
        f32x4v SBa, SBb, DBa, DBb, TB0, TB1;
        PREF(A, g0);
        for (;;) {
            int gn = g0 + EDGE_WAVES;
            { int gp = (gn < ngrp) ? gn : (ngrp - 1); PREF(B, gp); }
            asm volatile("" ::: "memory");
            compute16(g0, E, eI, g, lane, eA, dstA, winA, efA, dtA,
                      SAa, SAb, DAa, DAb, TA0, TA1,
                      tb, frg, clsb2, probs, out_mem);
            if (gn >= ngrp) break;
            g0 = gn;
            gn = g0 + EDGE_WAVES;
            { int gp = (gn < ngrp) ? gn : (ngrp - 1); PREF(A, gp); }
            asm volatile("" ::: "memory");
            compute16(g0, E, eI, g, lane, eB, dstB, winB, efB, dtB,
                      SBa, SBb, DBa, DBb, TB0, TB1,
                      tb, frg, clsb2, probs, out_mem);
            if (gn >= ngrp) break;
            g0 = gn;
        }
    }
#undef PREF
}

extern "C" void kernel_launch(void* const* d_in, const int* in_sizes, int n_in,
                              void* d_out, int out_size, void* d_ws, size_t ws_size,
                              hipStream_t stream) {
    const int*   src_ids   = (const int*)d_in[0];
    const int*   dst_ids   = (const int*)d_in[1];
    const float* edge_feat = (const float*)d_in[2];
    const float* delta_t   = (const float*)d_in[3];
    const float* memory    = (const float*)d_in[4];
    const float* msg_W1 = (const float*)d_in[5],  *msg_b1 = (const float*)d_in[6];
    const float* msg_W2 = (const float*)d_in[7],  *msg_b2 = (const float*)d_in[8];
    const float* w_ih   = (const float*)d_in[9],  *b_ih   = (const float*)d_in[10];
    const float* w_hh   = (const float*)d_in[11], *b_hh   = (const float*)d_in[12];
    const float* Wv     = (const float*)d_in[13], *bv     = (const float*)d_in[14];
    const float* Wo     = (const float*)d_in[15], *bo     = (const float*)d_in[16];
    const float* emb_W1 = (const float*)d_in[17], *emb_b1 = (const float*)d_in[18];
    const float* emb_W2 = (const float*)d_in[19], *emb_b2 = (const float*)d_in[20];
    const float* cls_W1 = (const float*)d_in[21], *cls_b1 = (const float*)d_in[22];
    const float* cls_W2 = (const float*)d_in[23], *cls_b2 = (const float*)d_in[24];

    int E = in_sizes[0];
    int N = in_sizes[4] / 32;
    int ngrp = (E + 15) / 16;

    int*   winner = (int*)d_ws;
    float* WSf    = (float*)((char*)d_ws + (size_t)N * sizeof(int));
    float* probs  = (float*)d_out;
    float* outmem = probs + E;

    hipMemsetAsync(winner, 0, (size_t)N * sizeof(int), stream);
    winner_k<<<(E + 255) / 256, 256, 0, stream>>>(dst_ids, winner, E);
    prep_wc_k<<<1, 256, 0, stream>>>(msg_W1, msg_b1, msg_b2, b_ih, b_hh,
                                     Wv, bv, Wo, bo, emb_W1, emb_b1, emb_b2,
                                     cls_b1, cls_W2, WSf);
    prep_frag_k<<<NFRAG, 256, 0, stream>>>(msg_W1, msg_W2, w_ih, w_hh,
                                           emb_W1, emb_W2, cls_W1, WSf);
    tgn_mfma16<<<GRID, BLK, 0, stream>>>(src_ids, dst_ids, edge_feat, delta_t,
                                         memory, cls_b2, WSf, winner,
                                         probs, outmem, E, N, ngrp);
}

// Round 16
// 269.819 us; speedup vs baseline: 1.4260x; 1.0028x over previous
//
#include <hip/hip_runtime.h>
#include <hip/hip_bf16.h>

typedef float  f32x4v __attribute__((ext_vector_type(4)));
typedef short  bf16x8 __attribute__((ext_vector_type(8)));

#define NFRAG   26
#define TB_F32  512                            // 16 tables x 32 f32
#define FRG_U16 (NFRAG*512)                    // 26 frags x 64 lanes x 8 bf16
#define SHARE_BYTES (TB_F32*4 + FRG_U16*2)     // 28672 B staged to LDS
#define SHARE_U4 (SHARE_BYTES/16)              // 1792 uint4
#define WC_OFF 7168                            // WC scratch offset in WS floats

#define BLK 512                                // 8 waves share one LDS image
#define COPY_BLOCKS 192
#define EDGE_BLOCKS 576
#define GRID (COPY_BLOCKS + EDGE_BLOCKS)       // 768 = 3 blocks/CU = 24 waves/CU
#define EDGE_WAVES (EDGE_BLOCKS * 8)           // 4608

#define MFMA(a,b,c) __builtin_amdgcn_mfma_f32_16x16x32_bf16(a,b,c,0,0,0)

__device__ __forceinline__ float sigf(float v) {
    return __builtin_amdgcn_rcpf(1.0f + __expf(-v));
}
__device__ __forceinline__ float tanhf_fast(float v) {
    float a = fabsf(v);
    float t = __expf(-2.0f * a);
    float r = (1.0f - t) * __builtin_amdgcn_rcpf(1.0f + t);
    return v < 0.0f ? -r : r;
}
__device__ __forceinline__ unsigned pk(float a, float b) {   // bf16(a) lo | bf16(b) hi
    union { __hip_bfloat162 h; unsigned u; } c;
    c.h = __float22bfloat162_rn(make_float2(a, b));
    return c.u;
}

union FragU { uint4 u4; bf16x8 s8; unsigned u[4]; };

__device__ __forceinline__ bf16x8 ldfrag(const unsigned short* frg, int idx_u16) {
    FragU c; c.u4 = *(const uint4*)(frg + idx_u16); return c.s8;
}
__device__ __forceinline__ f32x4v tbl(const float* tb, int idx_f32) {
    return *(const f32x4v*)(tb + idx_f32);
}
// In-register D->B relayout (R9-verified): consumer A-frags are k-permuted so
// the lane's 8 D values ARE its B fragment. Zero cross-lane, zero LDS.
__device__ __forceinline__ bf16x8 relayout_reg(f32x4v h0, f32x4v h1) {
    FragU c;
    c.u[0] = pk(h0[0], h0[1]); c.u[1] = pk(h0[2], h0[3]);
    c.u[2] = pk(h1[0], h1[1]); c.u[3] = pk(h1[2], h1[3]);
    return c.s8;
}

__global__ void winner_k(const int* __restrict__ dst_ids, int* __restrict__ winner, int E) {
    int e = blockIdx.x * 256 + threadIdx.x;
    if (e < E) atomicMax(winner + dst_ids[e], e + 1);
}

// Small single-block prep: bias/tail tables + folded attn matrix WC.
__global__ void prep_wc_k(const float* __restrict__ msg_W1, const float* __restrict__ msg_b1,
                          const float* __restrict__ msg_b2,
                          const float* __restrict__ b_ih, const float* __restrict__ b_hh,
                          const float* __restrict__ Wv, const float* __restrict__ bv,
                          const float* __restrict__ Wo, const float* __restrict__ bo,
                          const float* __restrict__ emb_W1, const float* __restrict__ emb_b1,
                          const float* __restrict__ emb_b2,
                          const float* __restrict__ cls_b1, const float* __restrict__ cls_W2,
                          float* __restrict__ WSf) {
    int t = threadIdx.x;  // 256 threads
    float* tb = WSf;
    float* WC = WSf + WC_OFF;
    if (t < 32) {
        int j = t;
        tb[0*32+j]  = msg_b1[j];
        tb[1*32+j]  = msg_W1[j*67+64];
        tb[2*32+j]  = msg_W1[j*67+65];
        tb[3*32+j]  = msg_W1[j*67+66];
        tb[4*32+j]  = msg_b2[j];
        tb[5*32+j]  = b_ih[32+j] + b_hh[32+j];     // z bias
        tb[6*32+j]  = b_ih[j] + b_hh[j];           // r bias
        tb[7*32+j]  = b_hh[64+j];                  // h_n bias
        tb[8*32+j]  = b_ih[64+j];                  // i_n bias
        float a = bo[j];
        for (int o = 0; o < 32; ++o) a += Wo[j*32+o] * bv[o];
        tb[9*32+j]  = a;                           // folded attn bias
        tb[10*32+j] = emb_b1[j];
        tb[11*32+j] = emb_W1[j*34+32];
        tb[12*32+j] = emb_W1[j*34+33];
        tb[13*32+j] = emb_b2[j];
        tb[14*32+j] = cls_b1[j];
        tb[15*32+j] = cls_W2[j];
    }
    for (int i = t; i < 1024; i += 256) {
        int j = i >> 5, k = i & 31;
        float a = 0.0f;
        for (int o = 0; o < 32; ++o) a += Wo[j*32+o] * Wv[o*32+k];
        WC[i] = a;
    }
}

// One block per fragment (26 blocks x 256 threads).
__global__ void prep_frag_k(const float* __restrict__ msg_W1,
                            const float* __restrict__ msg_W2,
                            const float* __restrict__ w_ih,
                            const float* __restrict__ w_hh,
                            const float* __restrict__ emb_W1,
                            const float* __restrict__ emb_W2,
                            const float* __restrict__ cls_W1,
                            float* __restrict__ WSf) {
    int f = blockIdx.x;
    unsigned short* frg = (unsigned short*)(WSf + TB_F32);
    const float* WC = WSf + WC_OFF;
    for (int k2 = threadIdx.x; k2 < 512; k2 += 256) {
        int l = k2 >> 3, i = k2 & 7;
        int r = l & 15, kb = ((l >> 4) << 3) + i;
        const float* P; int j0 = 0, k0 = 0, ld = 32;
        bool mapped = false;
        switch (f) {
            case 0:  P = msg_W1; j0 = 0;  k0 = 0;  ld = 67; break;
            case 1:  P = msg_W1; j0 = 0;  k0 = 32; ld = 67; break;
            case 2:  P = msg_W1; j0 = 16; k0 = 0;  ld = 67; break;
            case 3:  P = msg_W1; j0 = 16; k0 = 32; ld = 67; break;
            case 4:  P = msg_W2; j0 = 0;  mapped = true; break;
            case 5:  P = msg_W2; j0 = 16; mapped = true; break;
            case 6:  P = w_ih;   j0 = 32; mapped = true; break;   // z ih
            case 7:  P = w_hh;   j0 = 32; break;                  // z hh
            case 8:  P = w_ih;   j0 = 48; mapped = true; break;
            case 9:  P = w_hh;   j0 = 48; break;
            case 10: P = w_ih;   j0 = 0;  mapped = true; break;   // r ih
            case 11: P = w_hh;   j0 = 0;  break;
            case 12: P = w_ih;   j0 = 16; mapped = true; break;
            case 13: P = w_hh;   j0 = 16; break;
            case 14: P = w_hh;   j0 = 64; break;                  // n hh
            case 15: P = w_hh;   j0 = 80; break;
            case 16: P = w_ih;   j0 = 64; mapped = true; break;   // n ih
            case 17: P = w_ih;   j0 = 80; mapped = true; break;
            case 18: P = WC;     j0 = 0;  break;                  // folded attn
            case 19: P = WC;     j0 = 16; break;
            case 20: P = emb_W1; j0 = 0;  ld = 34; mapped = true; break;
            case 21: P = emb_W1; j0 = 16; ld = 34; mapped = true; break;
            case 22: P = emb_W2; j0 = 0;  mapped = true; break;
            case 23: P = emb_W2; j0 = 16; mapped = true; break;
            case 24: P = cls_W1; j0 = 0;  mapped = true; break;
            default: P = cls_W1; j0 = 16; mapped = true; break;
        }
        int kidx = kb;
        if (mapped) kidx = 16 * ((kb >> 2) & 1) + 4 * (kb >> 3) + (kb & 3);
        __hip_bfloat16 hv = __float2bfloat16(P[(j0 + r) * ld + k0 + kidx]);
        frg[f * 512 + k2] = *(unsigned short*)&hv;
    }
}

// Two independent dependency chains interleaved at source (R14-verified):
//   chain A: msg1 -> msg2 -> GRU(z,r,hn,n) -> blend -> winner store
//   chain B: attn -> emb1 -> emb2 -> cls  -> probs
__device__ __forceinline__ void compute16(
    int grp, int E, int eI, int g, int lane,
    int e, int dst, int winv, float2 ef, float dtv,
    f32x4v sa, f32x4v sb, f32x4v da, f32x4v db, f32x4v t0, f32x4v t1,
    const float* tb, const unsigned short* frg, float clsb2,
    float* __restrict__ probs, float* __restrict__ out_mem) {
    int ob = 0, tbo = 0;
    asm volatile("" : "+v"(ob), "+v"(tbo));  // block LICM of LDS frag/table reads

#define LFX(f) ldfrag(frg, (f) * 512 + lane * 8 + ob)
#define TBX(t_, jt_) tbl(tb, (t_) * 32 + (jt_) * 16 + 4 * g + tbo)

    FragU Bs, Bd;
    Bs.u[0] = pk(sa[0], sa[1]); Bs.u[1] = pk(sa[2], sa[3]);
    Bs.u[2] = pk(sb[0], sb[1]); Bs.u[3] = pk(sb[2], sb[3]);
    Bd.u[0] = pk(da[0], da[1]); Bd.u[1] = pk(da[2], da[3]);
    Bd.u[2] = pk(db[0], db[1]); Bd.u[3] = pk(db[2], db[3]);
    f32x4v dmt0 = t0, dmt1 = t1;

    // [A1] msg1: relu(W1 @ [sm, dm, ef, dt] + b1)
    f32x4v h0, h1;
    {
        f32x4v b0 = TBX(0,0), wa0 = TBX(1,0), wb0 = TBX(2,0), wc0 = TBX(3,0);
        f32x4v b1 = TBX(0,1), wa1 = TBX(1,1), wb1 = TBX(2,1), wc1 = TBX(3,1);
        f32x4v c0, c1;
#pragma unroll
        for (int i = 0; i < 4; ++i) {
            c0[i] = b0[i] + ef.x * wa0[i] + ef.y * wb0[i] + dtv * wc0[i];
            c1[i] = b1[i] + ef.x * wa1[i] + ef.y * wb1[i] + dtv * wc1[i];
        }
        c0 = MFMA(LFX(1), Bd.s8, c0); c0 = MFMA(LFX(0), Bs.s8, c0);
        c1 = MFMA(LFX(3), Bd.s8, c1); c1 = MFMA(LFX(2), Bs.s8, c1);
        h0 = c0; h1 = c1;
    }
    // [B1] attn (independent of A-chain: needs only Bd)
    f32x4v at0 = MFMA(LFX(18), Bd.s8, TBX(9,0));
    f32x4v at1 = MFMA(LFX(19), Bd.s8, TBX(9,1));
    // [A1 post] relu -> Bh
#pragma unroll
    for (int i = 0; i < 4; ++i) { h0[i] = fmaxf(h0[i], 0.0f); h1[i] = fmaxf(h1[i], 0.0f); }
    bf16x8 Bh = relayout_reg(h0, h1);
    // [A2] msg2
    f32x4v m0 = MFMA(LFX(4), Bh, TBX(4,0));
    f32x4v m1 = MFMA(LFX(5), Bh, TBX(4,1));
    // [B1 post] Ba ; [B2] emb1
    bf16x8 Ba = relayout_reg(at0, at1);
    f32x4v e10, e11;
    {
        f32x4v b0 = TBX(10,0), wa0 = TBX(11,0), wb0 = TBX(12,0);
        f32x4v b1 = TBX(10,1), wa1 = TBX(11,1), wb1 = TBX(12,1);
        f32x4v c0, c1;
#pragma unroll
        for (int i = 0; i < 4; ++i) {
            c0[i] = b0[i] + ef.x * wa0[i] + ef.y * wb0[i];
            c1[i] = b1[i] + ef.x * wa1[i] + ef.y * wb1[i];
        }
        e10 = MFMA(LFX(20), Ba, c0);
        e11 = MFMA(LFX(21), Ba, c1);
    }
    // [A2 post] Bm ; [A3] GRU z
    bf16x8 Bm = relayout_reg(m0, m1);
    f32x4v z0 = TBX(5,0); z0 = MFMA(LFX(7), Bd.s8, z0); z0 = MFMA(LFX(6), Bm, z0);
    f32x4v z1 = TBX(5,1); z1 = MFMA(LFX(9), Bd.s8, z1); z1 = MFMA(LFX(8), Bm, z1);
    // [B2 post] relu -> B1 ; [B3] emb2
#pragma unroll
    for (int i = 0; i < 4; ++i) { e10[i] = fmaxf(e10[i], 0.0f); e11[i] = fmaxf(e11[i], 0.0f); }
    bf16x8 B1 = relayout_reg(e10, e11);
    f32x4v e20 = MFMA(LFX(22), B1, TBX(13,0));
    f32x4v e21 = MFMA(LFX(23), B1, TBX(13,1));
    // [A3 post] sigmoid z ; [A4] r + hn
#pragma unroll
    for (int i = 0; i < 4; ++i) { z0[i] = sigf(z0[i]); z1[i] = sigf(z1[i]); }
    f32x4v r0 = TBX(6,0); r0 = MFMA(LFX(11), Bd.s8, r0); r0 = MFMA(LFX(10), Bm, r0);
    f32x4v r1 = TBX(6,1); r1 = MFMA(LFX(13), Bd.s8, r1); r1 = MFMA(LFX(12), Bm, r1);
    f32x4v hn0 = TBX(7,0); hn0 = MFMA(LFX(14), Bd.s8, hn0);
    f32x4v hn1 = TBX(7,1); hn1 = MFMA(LFX(15), Bd.s8, hn1);
    // [B3 post] B2 ; [B4] cls
    bf16x8 B2 = relayout_reg(e20, e21);
    f32x4v cc0 = MFMA(LFX(24), B2, TBX(14,0));
    f32x4v cc1 = MFMA(LFX(25), B2, TBX(14,1));
    // [A4 post] n pre-act + n MFMA
    f32x4v bin0 = TBX(8,0), bin1 = TBX(8,1);
    f32x4v np0, np1;
#pragma unroll
    for (int i = 0; i < 4; ++i) {
        np0[i] = fmaf(sigf(r0[i]), hn0[i], bin0[i]);
        np1[i] = fmaf(sigf(r1[i]), hn1[i], bin1[i]);
    }
    np0 = MFMA(LFX(16), Bm, np0);
    np1 = MFMA(LFX(17), Bm, np1);
    // [B4 post] cls dot
    float part = 0.0f;
    {
        f32x4v w20 = TBX(15,0), w21 = TBX(15,1);
#pragma unroll
        for (int i = 0; i < 4; ++i) {
            part = fmaf(fmaxf(cc0[i], 0.0f), w20[i], part);
            part = fmaf(fmaxf(cc1[i], 0.0f), w21[i], part);
        }
    }
    // [A5] blend + winner store
    f32x4v u0, u1;
#pragma unroll
    for (int i = 0; i < 4; ++i) {
        float n0 = tanhf_fast(np0[i]);
        float n1 = tanhf_fast(np1[i]);
        u0[i] = n0 + z0[i] * (dmt0[i] - n0);
        u1[i] = n1 + z1[i] * (dmt1[i] - n1);
    }
    if (winv == e + 1) {
        f32x4v* orow = (f32x4v*)(out_mem + (size_t)dst * 32);
        orow[g]     = u0;
        orow[4 + g] = u1;
    }
    // probs
    part += __shfl_xor(part, 16);
    part += __shfl_xor(part, 32);
    if (lane < 16) {
        int ee = grp * 16 + eI;
        if (ee < E) probs[ee] = sigf(part + clsb2);
    }
#undef LFX
#undef TBX
}

__global__ __launch_bounds__(BLK, 6) void tgn_mfma16(
    const int* __restrict__ src_ids, const int* __restrict__ dst_ids,
    const float* __restrict__ edge_feat, const float* __restrict__ delta_t,
    const float* __restrict__ memory, const float* __restrict__ cls_b2,
    const float* __restrict__ WSf, const int* __restrict__ winner,
    float* __restrict__ probs, float* __restrict__ out_mem,
    int E, int N, int ngrp) {
    __shared__ uint4 sbuf[SHARE_U4];
    int bid = blockIdx.x, tid = threadIdx.x;

    if (bid < COPY_BLOCKS) {
        // Copy workers: non-winner rows -> out_mem. NONTEMPORAL loads: this
        // stream has zero reuse — bypass L3 fill so the 256 MB `memory` gather
        // working set of the edge waves stays L3-resident. Stores stay normal
        // (L2 write-back merging; R6 showed NT stores are catastrophic).
        const f32x4v* m4 = (const f32x4v*)memory;
        f32x4v* o4 = (f32x4v*)out_mem;
        const long S = (long)COPY_BLOCKS * BLK;
        const long total4 = (long)N * 8;
        long i0 = (long)bid * BLK + tid;
        for (; i0 + 3 * S < total4; i0 += 4 * S) {
            long i1 = i0 + S, i2 = i0 + 2 * S, i3 = i0 + 3 * S;
            int w0 = winner[i0 >> 3];
            int w1 = winner[i1 >> 3];
            int w2 = winner[i2 >> 3];
            int w3 = winner[i3 >> 3];
            if (w0 == 0) o4[i0] = __builtin_nontemporal_load(m4 + i0);
            if (w1 == 0) o4[i1] = __builtin_nontemporal_load(m4 + i1);
            if (w2 == 0) o4[i2] = __builtin_nontemporal_load(m4 + i2);
            if (w3 == 0) o4[i3] = __builtin_nontemporal_load(m4 + i3);
        }
        for (; i0 < total4; i0 += S) {
            if (winner[i0 >> 3] == 0) o4[i0] = __builtin_nontemporal_load(m4 + i0);
        }
        return;
    }

    {   // stage tables + A-fragments into LDS (shared by 8 waves)
        const uint4* s = (const uint4*)WSf;
        for (int i = tid; i < SHARE_U4; i += BLK) sbuf[i] = s[i];
    }
    __syncthreads();
    const float* tb = (const float*)sbuf;
    const unsigned short* frg = (const unsigned short*)((const float*)sbuf + TB_F32);
    int wv = tid >> 6, lane = tid & 63;
    int eI = lane & 15, g = lane >> 4;
    int ewid = (bid - COPY_BLOCKS) * 8 + wv;
    float clsb2 = cls_b2[0];

#define PREF(P, G) do {                                                              \
    int ee = (G) * 16 + eI; if (ee >= E) ee = E - 1;                                 \
    e##P = ee;                                                                       \
    int sid = src_ids[ee]; dst##P = dst_ids[ee];                                     \
    ef##P = ((const float2*)edge_feat)[ee]; dt##P = delta_t[ee];                     \
    win##P = winner[dst##P];                                                         \
    const f32x4v* sp_ = (const f32x4v*)(memory + (size_t)sid * 32);                  \
    const f32x4v* dp_ = (const f32x4v*)(memory + (size_t)dst##P * 32);               \
    S##P##a = sp_[2*g]; S##P##b = sp_[2*g+1];                                        \
    D##P##a = dp_[2*g]; D##P##b = dp_[2*g+1];                                        \
    T##P##0 = dp_[g];   T##P##1 = dp_[4+g];                                          \
} while (0)

    int g0 = ewid;
    if (g0 < ngrp) {
        int eA, dstA, winA; float2 efA; float dtA;
        f32x4v SAa, SAb, DAa, DAb, TA0, TA1;
        int eB, dstB, winB; float2 efB; float dtB;
        f32x4v SBa, SBb, DBa, DBb, TB0, TB1;
        PREF(A, g0);
        for (;;) {
            int gn = g0 + EDGE_WAVES;
            { int gp = (gn < ngrp) ? gn : (ngrp - 1); PREF(B, gp); }
            asm volatile("" ::: "memory");
            compute16(g0, E, eI, g, lane, eA, dstA, winA, efA, dtA,
                      SAa, SAb, DAa, DAb, TA0, TA1,
                      tb, frg, clsb2, probs, out_mem);
            if (gn >= ngrp) break;
            g0 = gn;
            gn = g0 + EDGE_WAVES;
            { int gp = (gn < ngrp) ? gn : (ngrp - 1); PREF(A, gp); }
            asm volatile("" ::: "memory");
            compute16(g0, E, eI, g, lane, eB, dstB, winB, efB, dtB,
                      SBa, SBb, DBa, DBb, TB0, TB1,
                      tb, frg, clsb2, probs, out_mem);
            if (gn >= ngrp) break;
            g0 = gn;
        }
    }
#undef PREF
}

extern "C" void kernel_launch(void* const* d_in, const int* in_sizes, int n_in,
                              void* d_out, int out_size, void* d_ws, size_t ws_size,
                              hipStream_t stream) {
    const int*   src_ids   = (const int*)d_in[0];
    const int*   dst_ids   = (const int*)d_in[1];
    const float* edge_feat = (const float*)d_in[2];
    const float* delta_t   = (const float*)d_in[3];
    const float* memory    = (const float*)d_in[4];
    const float* msg_W1 = (const float*)d_in[5],  *msg_b1 = (const float*)d_in[6];
    const float* msg_W2 = (const float*)d_in[7],  *msg_b2 = (const float*)d_in[8];
    const float* w_ih   = (const float*)d_in[9],  *b_ih   = (const float*)d_in[10];
    const float* w_hh   = (const float*)d_in[11], *b_hh   = (const float*)d_in[12];
    const float* Wv     = (const float*)d_in[13], *bv     = (const float*)d_in[14];
    const float* Wo     = (const float*)d_in[15], *bo     = (const float*)d_in[16];
    const float* emb_W1 = (const float*)d_in[17], *emb_b1 = (const float*)d_in[18];
    const float* emb_W2 = (const float*)d_in[19], *emb_b2 = (const float*)d_in[20];
    const float* cls_W1 = (const float*)d_in[21], *cls_b1 = (const float*)d_in[22];
    const float* cls_W2 = (const float*)d_in[23], *cls_b2 = (const float*)d_in[24];

    int E = in_sizes[0];
    int N = in_sizes[4] / 32;
    int ngrp = (E + 15) / 16;

    int*   winner = (int*)d_ws;
    float* WSf    = (float*)((char*)d_ws + (size_t)N * sizeof(int));
    float* probs  = (float*)d_out;
    float* outmem = probs + E;

    hipMemsetAsync(winner, 0, (size_t)N * sizeof(int), stream);
    winner_k<<<(E + 255) / 256, 256, 0, stream>>>(dst_ids, winner, E);
    prep_wc_k<<<1, 256, 0, stream>>>(msg_W1, msg_b1, msg_b2, b_ih, b_hh,
                                     Wv, bv, Wo, bo, emb_W1, emb_b1, emb_b2,
                                     cls_b1, cls_W2, WSf);
    prep_frag_k<<<NFRAG, 256, 0, stream>>>(msg_W1, msg_W2, w_ih, w_hh,
                                           emb_W1, emb_W2, cls_W1, WSf);
    tgn_mfma16<<<GRID, BLK, 0, stream>>>(src_ids, dst_ids, edge_feat, delta_t,
                                         memory, cls_b2, WSf, winner,
                                         probs, outmem, E, N, ngrp);
}